// Round 1
// baseline (3943.223 us; speedup 1.0000x reference)
//
#include <hip/hip_runtime.h>
#include <hip/hip_bf16.h>
#include <math.h>

#define N_NODES_C 100000

__device__ __forceinline__ void fatomic_add(float* p, float v) {
    unsafeAtomicAdd(p, v);   // HW global_atomic_add_f32 (gfx90a+), avoids CAS loop
}

// ---- degrees: out_deg[src]++, in_deg[dst]++ ------------------------------
__global__ void deg_kernel(const int* __restrict__ src, const int* __restrict__ dst,
                           float* __restrict__ outdeg, float* __restrict__ indeg, int E) {
    int i = blockIdx.x * 256 + threadIdx.x;
    if (i < E) {
        fatomic_add(&outdeg[src[i]], 1.0f);
        fatomic_add(&indeg[dst[i]], 1.0f);
    }
}

// ---- norms: rsqrt(deg) ---------------------------------------------------
__global__ void norm_kernel(const float* __restrict__ outdeg, const float* __restrict__ indeg,
                            float* __restrict__ nsrc, float* __restrict__ ndst, int N) {
    int i = blockIdx.x * 256 + threadIdx.x;
    if (i < N) {
        nsrc[i] = rsqrtf(outdeg[i]);
        ndst[i] = rsqrtf(indeg[i]);
    }
}

// ---- GEMM1: h1[n][j] = nsrc[n] * sum_k feat[n][k] * W1[k][j]   (j<32) ----
// 32 nodes/block, 256 threads: j = t&31, group g = t>>5 handles 4 nodes.
__global__ __launch_bounds__(256) void gemm1_kernel(
    const float* __restrict__ feat, const float* __restrict__ W1,
    const float* __restrict__ nsrc, float* __restrict__ h1, int N) {
    __shared__ float sW[256 * 32];   // 32 KB
    __shared__ float sF[32 * 256];   // 32 KB
    const int t = threadIdx.x;
    const int n0 = blockIdx.x * 32;

    const float4* W4 = (const float4*)W1;          // 2048 float4
    float4* sW4 = (float4*)sW;
    #pragma unroll
    for (int i = 0; i < 8; ++i) sW4[t + 256 * i] = W4[t + 256 * i];

    const float4* F4 = (const float4*)(feat + (size_t)n0 * 256);  // 2048 float4
    float4* sF4 = (float4*)sF;
    #pragma unroll
    for (int i = 0; i < 8; ++i) sF4[t + 256 * i] = F4[t + 256 * i];   // 3125*32==100000 exact

    __syncthreads();

    const int j = t & 31;
    const int g = t >> 5;            // 0..7, 4 nodes each
    float acc0 = 0.f, acc1 = 0.f, acc2 = 0.f, acc3 = 0.f;
    const float* f0 = &sF[(g * 4 + 0) * 256];
    const float* f1 = &sF[(g * 4 + 1) * 256];
    const float* f2 = &sF[(g * 4 + 2) * 256];
    const float* f3 = &sF[(g * 4 + 3) * 256];
    #pragma unroll 4
    for (int k = 0; k < 256; ++k) {
        const float w = sW[k * 32 + j];
        acc0 += f0[k] * w;
        acc1 += f1[k] * w;
        acc2 += f2[k] * w;
        acc3 += f3[k] * w;
    }
    const int n = n0 + g * 4;
    h1[(size_t)(n + 0) * 32 + j] = acc0 * nsrc[n + 0];
    h1[(size_t)(n + 1) * 32 + j] = acc1 * nsrc[n + 1];
    h1[(size_t)(n + 2) * 32 + j] = acc2 * nsrc[n + 2];
    h1[(size_t)(n + 3) * 32 + j] = acc3 * nsrc[n + 3];
}

// ---- scatter1: agg1[dst] += h1[src], 32 feats = 8 float4 chunks/edge -----
__global__ void scatter1_kernel(const int* __restrict__ src, const int* __restrict__ dst,
                                const float* __restrict__ h1, float* __restrict__ agg1, int E) {
    int tt = blockIdx.x * 256 + threadIdx.x;
    if (tt >= E * 8) return;
    const int e = tt >> 3, c = tt & 7;
    const int s = src[e], d = dst[e];
    const float4 v = *(const float4*)(h1 + (size_t)s * 32 + c * 4);
    float* p = agg1 + (size_t)d * 32 + c * 4;
    fatomic_add(p + 0, v.x);
    fatomic_add(p + 1, v.y);
    fatomic_add(p + 2, v.z);
    fatomic_add(p + 3, v.w);
}

// ---- epilogue1: x1 = relu(agg1 * ndst + b1), in place --------------------
__global__ void epilogue1_kernel(float* __restrict__ agg1, const float* __restrict__ ndst,
                                 const float* __restrict__ b1, int N) {
    int t = blockIdx.x * 256 + threadIdx.x;
    if (t < N * 32) {
        const int n = t >> 5, j = t & 31;
        const float v = agg1[t] * ndst[n] + b1[j];
        agg1[t] = fmaxf(v, 0.f);
    }
}

// ---- GEMM2: h2[n][j] = nsrc[n] * sum_k x1[n][k] * W2[k][j]   (j<40) ------
// 8 nodes/block, 320 threads (5 waves): j = t%40, ln = t/40.
__global__ __launch_bounds__(320) void gemm2_kernel(
    const float* __restrict__ x1, const float* __restrict__ W2,
    const float* __restrict__ nsrc, float* __restrict__ h2, int N) {
    __shared__ float sW[32 * 40];    // 5 KB
    __shared__ float sX[8 * 32];     // 1 KB
    const int t = threadIdx.x;
    const int n0 = blockIdx.x * 8;
    for (int i = t; i < 1280; i += 320) sW[i] = W2[i];
    if (t < 256) sX[t] = x1[(size_t)n0 * 32 + t];   // 12500*8==100000 exact
    __syncthreads();
    const int j = t % 40;
    const int ln = t / 40;           // 0..7
    const float* xr = &sX[ln * 32];
    float s = 0.f;
    #pragma unroll
    for (int k = 0; k < 32; ++k) s += xr[k] * sW[k * 40 + j];
    const int n = n0 + ln;
    h2[(size_t)n * 40 + j] = s * nsrc[n];
}

// ---- scatter2: agg2[dst] += h2[src], 40 feats = 10 float4 chunks/edge ----
__global__ void scatter2_kernel(const int* __restrict__ src, const int* __restrict__ dst,
                                const float* __restrict__ h2, float* __restrict__ agg2, int E) {
    int tt = blockIdx.x * 256 + threadIdx.x;
    if (tt >= E * 10) return;
    const int e = tt / 10, c = tt - e * 10;
    const int s = src[e], d = dst[e];
    const float4 v = *(const float4*)(h2 + (size_t)s * 40 + c * 4);
    float* p = agg2 + (size_t)d * 40 + c * 4;
    fatomic_add(p + 0, v.x);
    fatomic_add(p + 1, v.y);
    fatomic_add(p + 2, v.z);
    fatomic_add(p + 3, v.w);
}

// ---- final: out = log_softmax(agg2 * ndst + b2), one wave per node -------
__global__ __launch_bounds__(256) void final_kernel(
    const float* __restrict__ agg2, const float* __restrict__ ndst,
    const float* __restrict__ b2, float* __restrict__ out, int N) {
    const int lane = threadIdx.x & 63;
    const int n = blockIdx.x * 4 + (threadIdx.x >> 6);
    if (n >= N) return;
    float v = -INFINITY;
    if (lane < 40) v = agg2[(size_t)n * 40 + lane] * ndst[n] + b2[lane];
    float m = v;
    #pragma unroll
    for (int off = 32; off; off >>= 1) m = fmaxf(m, __shfl_xor(m, off, 64));
    float e = (lane < 40) ? expf(v - m) : 0.f;
    float s = e;
    #pragma unroll
    for (int off = 32; off; off >>= 1) s += __shfl_xor(s, off, 64);
    if (lane < 40) out[(size_t)n * 40 + lane] = v - m - logf(s);
}

extern "C" void kernel_launch(void* const* d_in, const int* in_sizes, int n_in,
                              void* d_out, int out_size, void* d_ws, size_t ws_size,
                              hipStream_t stream) {
    const float* feat = (const float*)d_in[0];
    const int*   src  = (const int*)d_in[1];
    const int*   dst  = (const int*)d_in[2];
    const float* W1   = (const float*)d_in[3];
    const float* b1   = (const float*)d_in[4];
    const float* W2   = (const float*)d_in[5];
    const float* b2   = (const float*)d_in[6];
    float* out = (float*)d_out;

    const int N = in_sizes[0] / 256;   // 100000
    const int E = in_sizes[1];         // 3300000

    // workspace layout (fp32): 148*N floats = 59.2 MB
    float* ws     = (float*)d_ws;
    float* outdeg = ws;                       // N
    float* indeg  = outdeg + N;               // N
    float* nsrc   = indeg + N;                // N
    float* ndst   = nsrc + N;                 // N
    float* h1     = ndst + N;                 // 32N
    float* agg1   = h1 + (size_t)32 * N;      // 32N  (becomes x1 in place)
    float* h2     = agg1 + (size_t)32 * N;    // 40N
    float* agg2   = h2 + (size_t)40 * N;      // 40N

    hipMemsetAsync(outdeg, 0, sizeof(float) * 2 * (size_t)N, stream);  // outdeg+indeg
    hipMemsetAsync(agg1,   0, sizeof(float) * 32 * (size_t)N, stream);
    hipMemsetAsync(agg2,   0, sizeof(float) * 40 * (size_t)N, stream);

    deg_kernel<<<(E + 255) / 256, 256, 0, stream>>>(src, dst, outdeg, indeg, E);
    norm_kernel<<<(N + 255) / 256, 256, 0, stream>>>(outdeg, indeg, nsrc, ndst, N);
    gemm1_kernel<<<N / 32, 256, 0, stream>>>(feat, W1, nsrc, h1, N);
    scatter1_kernel<<<(E * 8 + 255) / 256, 256, 0, stream>>>(src, dst, h1, agg1, E);
    epilogue1_kernel<<<(N * 32 + 255) / 256, 256, 0, stream>>>(agg1, ndst, b1, N);
    gemm2_kernel<<<N / 8, 320, 0, stream>>>(agg1, W2, nsrc, h2, N);
    scatter2_kernel<<<(E * 10 + 255) / 256, 256, 0, stream>>>(src, dst, h2, agg2, E);
    final_kernel<<<(N + 3) / 4, 256, 0, stream>>>(agg2, ndst, b2, out, N);
}

// Round 2
// 951.690 us; speedup vs baseline: 4.1434x; 4.1434x over previous
//
#include <hip/hip_runtime.h>
#include <hip/hip_bf16.h>
#include <math.h>

// ---- degree histograms (int atomics) -------------------------------------
__global__ void hist_kernel(const int* __restrict__ src, const int* __restrict__ dst,
                            int* __restrict__ outdeg, int* __restrict__ indeg, int E) {
    int i = blockIdx.x * 256 + threadIdx.x;
    if (i < E) {
        atomicAdd(&outdeg[src[i]], 1);
        atomicAdd(&indeg[dst[i]], 1);
    }
}

// ---- norms: rsqrt(deg) ----------------------------------------------------
__global__ void norm_kernel(const int* __restrict__ outdeg, const int* __restrict__ indeg,
                            float* __restrict__ nsrc, float* __restrict__ ndst, int N) {
    int i = blockIdx.x * 256 + threadIdx.x;
    if (i < N) {
        nsrc[i] = rsqrtf((float)outdeg[i]);
        ndst[i] = rsqrtf((float)indeg[i]);
    }
}

// ---- exclusive scan of indeg -> rowpos (3 phases) -------------------------
// phase 1: per-block (1024 elems) exclusive scan + block total
__global__ __launch_bounds__(256) void scan1_kernel(const int* __restrict__ indeg,
        int* __restrict__ rowpos, int* __restrict__ bsum, int N) {
    __shared__ int s[256];
    const int t = threadIdx.x;
    const int base = blockIdx.x * 1024 + t * 4;
    int v0 = 0, v1 = 0, v2 = 0, v3 = 0;
    if (base + 3 < N) {
        const int4 q = *(const int4*)(indeg + base);
        v0 = q.x; v1 = q.y; v2 = q.z; v3 = q.w;
    } else {
        if (base + 0 < N) v0 = indeg[base + 0];
        if (base + 1 < N) v1 = indeg[base + 1];
        if (base + 2 < N) v2 = indeg[base + 2];
        if (base + 3 < N) v3 = indeg[base + 3];
    }
    const int tsum = v0 + v1 + v2 + v3;
    s[t] = tsum;
    __syncthreads();
    for (int off = 1; off < 256; off <<= 1) {
        int x = (t >= off) ? s[t - off] : 0;
        __syncthreads();
        s[t] += x;
        __syncthreads();
    }
    const int excl = s[t] - tsum;
    if (t == 255) bsum[blockIdx.x] = s[255];
    if (base + 3 < N) {
        int4 w; w.x = excl; w.y = excl + v0; w.z = excl + v0 + v1; w.w = excl + v0 + v1 + v2;
        *(int4*)(rowpos + base) = w;
    } else {
        if (base + 0 < N) rowpos[base + 0] = excl;
        if (base + 1 < N) rowpos[base + 1] = excl + v0;
        if (base + 2 < N) rowpos[base + 2] = excl + v0 + v1;
        if (base + 3 < N) rowpos[base + 3] = excl + v0 + v1 + v2;
    }
}

// phase 2: single-block exclusive scan of block sums (G <= 128)
__global__ void scan2_kernel(int* __restrict__ bsum, int G) {
    __shared__ int s[128];
    const int t = threadIdx.x;
    const int v = (t < G) ? bsum[t] : 0;
    s[t] = v;
    __syncthreads();
    for (int off = 1; off < 128; off <<= 1) {
        int x = (t >= off) ? s[t - off] : 0;
        __syncthreads();
        s[t] += x;
        __syncthreads();
    }
    if (t < G) bsum[t] = s[t] - v;
}

// phase 3: add block offsets
__global__ void scan3_kernel(int* __restrict__ rowpos, const int* __restrict__ bsum, int N) {
    int i = blockIdx.x * 256 + threadIdx.x;
    if (i < N) rowpos[i] += bsum[i >> 10];
}

// ---- CSR fill: csr_src[pos++] = src; rowpos becomes row_end ---------------
__global__ void fill_kernel(const int* __restrict__ src, const int* __restrict__ dst,
                            int* __restrict__ rowpos, int* __restrict__ csr_src, int E) {
    int e = blockIdx.x * 256 + threadIdx.x;
    if (e < E) {
        const int d = dst[e];
        const int pos = atomicAdd(&rowpos[d], 1);
        csr_src[pos] = src[e];
    }
}

// ---- GEMM1: h1[n][j] = nsrc[n] * sum_k feat[n][k] * W1[k][j]   (j<32) ----
__global__ __launch_bounds__(256) void gemm1_kernel(
    const float* __restrict__ feat, const float* __restrict__ W1,
    const float* __restrict__ nsrc, float* __restrict__ h1, int N) {
    __shared__ float sW[256 * 32];   // 32 KB
    __shared__ float sF[32 * 256];   // 32 KB
    const int t = threadIdx.x;
    const int n0 = blockIdx.x * 32;

    const float4* W4 = (const float4*)W1;
    float4* sW4 = (float4*)sW;
    #pragma unroll
    for (int i = 0; i < 8; ++i) sW4[t + 256 * i] = W4[t + 256 * i];

    const float4* F4 = (const float4*)(feat + (size_t)n0 * 256);
    float4* sF4 = (float4*)sF;
    #pragma unroll
    for (int i = 0; i < 8; ++i) sF4[t + 256 * i] = F4[t + 256 * i];

    __syncthreads();

    const int j = t & 31;
    const int g = t >> 5;
    float acc0 = 0.f, acc1 = 0.f, acc2 = 0.f, acc3 = 0.f;
    const float* f0 = &sF[(g * 4 + 0) * 256];
    const float* f1 = &sF[(g * 4 + 1) * 256];
    const float* f2 = &sF[(g * 4 + 2) * 256];
    const float* f3 = &sF[(g * 4 + 3) * 256];
    #pragma unroll 4
    for (int k = 0; k < 256; ++k) {
        const float w = sW[k * 32 + j];
        acc0 += f0[k] * w;
        acc1 += f1[k] * w;
        acc2 += f2[k] * w;
        acc3 += f3[k] * w;
    }
    const int n = n0 + g * 4;
    h1[(size_t)(n + 0) * 32 + j] = acc0 * nsrc[n + 0];
    h1[(size_t)(n + 1) * 32 + j] = acc1 * nsrc[n + 1];
    h1[(size_t)(n + 2) * 32 + j] = acc2 * nsrc[n + 2];
    h1[(size_t)(n + 3) * 32 + j] = acc3 * nsrc[n + 3];
}

// ---- agg1: x1[n] = relu(ndst[n] * sum_{s in N(n)} h1[s] + b1) -------------
// 32 nodes/block, 8 lanes/node, one float4 chunk per lane.
__global__ __launch_bounds__(256) void agg1_kernel(
    const int* __restrict__ csr_src, const int* __restrict__ rowend,
    const int* __restrict__ indeg, const float* __restrict__ h1,
    const float* __restrict__ ndst, const float* __restrict__ b1,
    float* __restrict__ x1, int N) {
    const int t = threadIdx.x;
    const int n = blockIdx.x * 32 + (t >> 3);
    const int c = t & 7;
    const int re = rowend[n];
    const int rs = re - indeg[n];
    float4 acc = {0.f, 0.f, 0.f, 0.f};
    for (int k = rs; k < re; ++k) {
        const int s = csr_src[k];
        const float4 v = *(const float4*)(h1 + (size_t)s * 32 + c * 4);
        acc.x += v.x; acc.y += v.y; acc.z += v.z; acc.w += v.w;
    }
    const float nd = ndst[n];
    const float4 bb = *(const float4*)(b1 + c * 4);
    float4 o;
    o.x = fmaxf(acc.x * nd + bb.x, 0.f);
    o.y = fmaxf(acc.y * nd + bb.y, 0.f);
    o.z = fmaxf(acc.z * nd + bb.z, 0.f);
    o.w = fmaxf(acc.w * nd + bb.w, 0.f);
    *(float4*)(x1 + (size_t)n * 32 + c * 4) = o;
}

// ---- GEMM2: h2[n][j] = nsrc[n] * sum_k x1[n][k] * W2[k][j]   (j<40) ------
__global__ __launch_bounds__(320) void gemm2_kernel(
    const float* __restrict__ x1, const float* __restrict__ W2,
    const float* __restrict__ nsrc, float* __restrict__ h2, int N) {
    __shared__ float sW[32 * 40];
    __shared__ float sX[8 * 32];
    const int t = threadIdx.x;
    const int n0 = blockIdx.x * 8;
    for (int i = t; i < 1280; i += 320) sW[i] = W2[i];
    if (t < 256) sX[t] = x1[(size_t)n0 * 32 + t];
    __syncthreads();
    const int j = t % 40;
    const int ln = t / 40;
    const float* xr = &sX[ln * 32];
    float s = 0.f;
    #pragma unroll
    for (int k = 0; k < 32; ++k) s += xr[k] * sW[k * 40 + j];
    const int n = n0 + ln;
    h2[(size_t)n * 40 + j] = s * nsrc[n];
}

// ---- agg2: agg2[n] = sum_{s in N(n)} h2[s] --------------------------------
// 32 nodes/block, 10 lanes/node, one float4 chunk per lane (block = 320).
__global__ __launch_bounds__(320) void agg2_kernel(
    const int* __restrict__ csr_src, const int* __restrict__ rowend,
    const int* __restrict__ indeg, const float* __restrict__ h2,
    float* __restrict__ agg2, int N) {
    const int t = threadIdx.x;
    const int n = blockIdx.x * 32 + t / 10;
    const int c = t % 10;
    const int re = rowend[n];
    const int rs = re - indeg[n];
    float4 acc = {0.f, 0.f, 0.f, 0.f};
    for (int k = rs; k < re; ++k) {
        const int s = csr_src[k];
        const float4 v = *(const float4*)(h2 + (size_t)s * 40 + c * 4);
        acc.x += v.x; acc.y += v.y; acc.z += v.z; acc.w += v.w;
    }
    *(float4*)(agg2 + (size_t)n * 40 + c * 4) = acc;
}

// ---- final: out = log_softmax(agg2 * ndst + b2), one wave per node --------
__global__ __launch_bounds__(256) void final_kernel(
    const float* __restrict__ agg2, const float* __restrict__ ndst,
    const float* __restrict__ b2, float* __restrict__ out, int N) {
    const int lane = threadIdx.x & 63;
    const int n = blockIdx.x * 4 + (threadIdx.x >> 6);
    if (n >= N) return;
    float v = -INFINITY;
    if (lane < 40) v = agg2[(size_t)n * 40 + lane] * ndst[n] + b2[lane];
    float m = v;
    #pragma unroll
    for (int off = 32; off; off >>= 1) m = fmaxf(m, __shfl_xor(m, off, 64));
    float e = (lane < 40) ? expf(v - m) : 0.f;
    float s = e;
    #pragma unroll
    for (int off = 32; off; off >>= 1) s += __shfl_xor(s, off, 64);
    if (lane < 40) out[(size_t)n * 40 + lane] = v - m - logf(s);
}

extern "C" void kernel_launch(void* const* d_in, const int* in_sizes, int n_in,
                              void* d_out, int out_size, void* d_ws, size_t ws_size,
                              hipStream_t stream) {
    const float* feat = (const float*)d_in[0];
    const int*   src  = (const int*)d_in[1];
    const int*   dst  = (const int*)d_in[2];
    const float* W1   = (const float*)d_in[3];
    const float* b1   = (const float*)d_in[4];
    const float* W2   = (const float*)d_in[5];
    const float* b2   = (const float*)d_in[6];
    float* out = (float*)d_out;

    const int N = in_sizes[0] / 256;   // 100000
    const int E = in_sizes[1];         // 3300000

    // workspace layout: 106N floats + (3N + 128 + E) ints ~= 56.6 MB
    // overlay: A = h1 (layer1) then agg2 (layer2, 40N spans A + first 8N of B)
    float* nsrc = (float*)d_ws;               // N
    float* ndst = nsrc + N;                   // N
    float* A    = ndst + N;                   // 32N : h1, later agg2 (40N)
    float* B    = A + (size_t)32 * N;         // 32N : x1
    float* C    = B + (size_t)32 * N;         // 40N : h2
    int* outdeg_i = (int*)(C + (size_t)40 * N);  // N
    int* indeg_i  = outdeg_i + N;             // N
    int* rowpos   = indeg_i + N;              // N (excl-scan -> row_end after fill)
    int* bsum     = rowpos + N;               // 128
    int* csr_src  = bsum + 128;               // E

    float* h1   = A;
    float* x1   = B;
    float* h2   = C;
    float* agg2 = A;   // 40N, overlays dead h1 + first 8N of dead x1

    hipMemsetAsync(outdeg_i, 0, sizeof(int) * 2 * (size_t)N, stream);

    const int G = (N + 1023) / 1024;   // 98 blocks for scan1

    hist_kernel<<<(E + 255) / 256, 256, 0, stream>>>(src, dst, outdeg_i, indeg_i, E);
    norm_kernel<<<(N + 255) / 256, 256, 0, stream>>>(outdeg_i, indeg_i, nsrc, ndst, N);
    scan1_kernel<<<G, 256, 0, stream>>>(indeg_i, rowpos, bsum, N);
    scan2_kernel<<<1, 128, 0, stream>>>(bsum, G);
    scan3_kernel<<<(N + 255) / 256, 256, 0, stream>>>(rowpos, bsum, N);
    fill_kernel<<<(E + 255) / 256, 256, 0, stream>>>(src, dst, rowpos, csr_src, E);

    gemm1_kernel<<<N / 32, 256, 0, stream>>>(feat, W1, nsrc, h1, N);
    agg1_kernel<<<N / 32, 256, 0, stream>>>(csr_src, rowpos, indeg_i, h1, ndst, b1, x1, N);
    gemm2_kernel<<<N / 8, 320, 0, stream>>>(x1, W2, nsrc, h2, N);
    agg2_kernel<<<N / 32, 320, 0, stream>>>(csr_src, rowpos, indeg_i, h2, agg2, N);
    final_kernel<<<(N + 3) / 4, 256, 0, stream>>>(agg2, ndst, b2, out, N);
}

// Round 3
// 742.259 us; speedup vs baseline: 5.3125x; 1.2822x over previous
//
#include <hip/hip_runtime.h>
#include <hip/hip_bf16.h>
#include <math.h>

#define BSHIFT 8                 // 256 dst-nodes per bucket
#define NBUCK(N) (((N) + 255) >> 8)

// ---- degree histograms (int atomics) -------------------------------------
__global__ void hist_kernel(const int* __restrict__ src, const int* __restrict__ dst,
                            int* __restrict__ outdeg, int* __restrict__ indeg, int E) {
    int i = blockIdx.x * 256 + threadIdx.x;
    if (i < E) {
        atomicAdd(&outdeg[src[i]], 1);
        atomicAdd(&indeg[dst[i]], 1);
    }
}

// ---- norms: rsqrt(deg) ----------------------------------------------------
__global__ void norm_kernel(const int* __restrict__ outdeg, const int* __restrict__ indeg,
                            float* __restrict__ nsrc, float* __restrict__ ndst, int N) {
    int i = blockIdx.x * 256 + threadIdx.x;
    if (i < N) {
        nsrc[i] = rsqrtf((float)outdeg[i]);
        ndst[i] = rsqrtf((float)indeg[i]);
    }
}

// ---- exclusive scan of indeg -> rowpos (rowstart), 3 phases ---------------
__global__ __launch_bounds__(256) void scan1_kernel(const int* __restrict__ indeg,
        int* __restrict__ rowpos, int* __restrict__ bsum, int N) {
    __shared__ int s[256];
    const int t = threadIdx.x;
    const int base = blockIdx.x * 1024 + t * 4;
    int v0 = 0, v1 = 0, v2 = 0, v3 = 0;
    if (base + 3 < N) {
        const int4 q = *(const int4*)(indeg + base);
        v0 = q.x; v1 = q.y; v2 = q.z; v3 = q.w;
    } else {
        if (base + 0 < N) v0 = indeg[base + 0];
        if (base + 1 < N) v1 = indeg[base + 1];
        if (base + 2 < N) v2 = indeg[base + 2];
        if (base + 3 < N) v3 = indeg[base + 3];
    }
    const int tsum = v0 + v1 + v2 + v3;
    s[t] = tsum;
    __syncthreads();
    for (int off = 1; off < 256; off <<= 1) {
        int x = (t >= off) ? s[t - off] : 0;
        __syncthreads();
        s[t] += x;
        __syncthreads();
    }
    const int excl = s[t] - tsum;
    if (t == 255) bsum[blockIdx.x] = s[255];
    if (base + 3 < N) {
        int4 w; w.x = excl; w.y = excl + v0; w.z = excl + v0 + v1; w.w = excl + v0 + v1 + v2;
        *(int4*)(rowpos + base) = w;
    } else {
        if (base + 0 < N) rowpos[base + 0] = excl;
        if (base + 1 < N) rowpos[base + 1] = excl + v0;
        if (base + 2 < N) rowpos[base + 2] = excl + v0 + v1;
        if (base + 3 < N) rowpos[base + 3] = excl + v0 + v1 + v2;
    }
}

__global__ void scan2_kernel(int* __restrict__ bsum, int G) {
    __shared__ int s[128];
    const int t = threadIdx.x;
    const int v = (t < G) ? bsum[t] : 0;
    s[t] = v;
    __syncthreads();
    for (int off = 1; off < 128; off <<= 1) {
        int x = (t >= off) ? s[t - off] : 0;
        __syncthreads();
        s[t] += x;
        __syncthreads();
    }
    if (t < G) bsum[t] = s[t] - v;
}

__global__ void scan3_kernel(int* __restrict__ rowpos, const int* __restrict__ bsum, int N) {
    int i = blockIdx.x * 256 + threadIdx.x;
    if (i < N) rowpos[i] += bsum[i >> 10];
}

// ---- init bucket cursors: gpos[b] = rowstart of node b*256 ----------------
__global__ void initgpos_kernel(const int* __restrict__ rowpos, int* __restrict__ gpos,
                                int N, int K) {
    int b = blockIdx.x * 256 + threadIdx.x;
    if (b < K) gpos[b] = rowpos[b << BSHIFT];
}

// ---- pass 1: partition edges into dst-buckets (packed local_dst|src) ------
// tile = 8192 edges, 256 threads, 32 edges/thread.
__global__ __launch_bounds__(256) void part_kernel(
    const int* __restrict__ src, const int* __restrict__ dst,
    int* __restrict__ gpos, int* __restrict__ gbuf, int E, int K) {
    __shared__ int cnt[512];
    __shared__ int base[512];
    const int t = threadIdx.x;
    const int tile = blockIdx.x * 8192;
    for (int i = t; i < K; i += 256) cnt[i] = 0;
    __syncthreads();

    int dv[32];
    #pragma unroll
    for (int i = 0; i < 32; ++i) {
        const int e = tile + i * 256 + t;
        dv[i] = (e < E) ? dst[e] : -1;
        if (dv[i] >= 0) atomicAdd(&cnt[dv[i] >> BSHIFT], 1);
    }
    __syncthreads();
    for (int i = t; i < K; i += 256) {
        base[i] = atomicAdd(&gpos[i], cnt[i]);
        cnt[i] = 0;
    }
    __syncthreads();
    #pragma unroll
    for (int i = 0; i < 32; ++i) {
        const int e = tile + i * 256 + t;
        if (dv[i] >= 0) {
            const int b = dv[i] >> BSHIFT;
            const int idx = base[b] + atomicAdd(&cnt[b], 1);
            gbuf[idx] = ((dv[i] & 255) << 17) | src[e];
        }
    }
}

// ---- pass 2: within-bucket reorder to exact CSR ---------------------------
// one block per bucket; LDS cursors from rowpos; writes stay in one ~34 KB
// region owned by this block (single XCD L2 -> full-line merges).
__global__ __launch_bounds__(256) void fill2_kernel(
    const int* __restrict__ rowpos, const int* __restrict__ gbuf,
    int* __restrict__ csr_src, int N, int E, int K) {
    __shared__ int cur[256];
    const int t = threadIdx.x;
    const int b = blockIdx.x;
    const int n0 = b << BSHIFT;
    if (n0 + t < N) cur[t] = rowpos[n0 + t];
    const int rstart = rowpos[n0];
    const int rend = (b == K - 1) ? E : rowpos[(b + 1) << BSHIFT];
    __syncthreads();
    for (int idx = rstart + t; idx < rend; idx += 256) {
        const int p = gbuf[idx];
        const int ld = p >> 17;
        const int s = p & 131071;
        const int pos = atomicAdd(&cur[ld], 1);
        csr_src[pos] = s;
    }
}

// ---- GEMM1: h1[n][j] = nsrc[n] * sum_k feat[n][k] * W1[k][j]   (j<32) ----
__global__ __launch_bounds__(256) void gemm1_kernel(
    const float* __restrict__ feat, const float* __restrict__ W1,
    const float* __restrict__ nsrc, float* __restrict__ h1, int N) {
    __shared__ float sW[256 * 32];   // 32 KB
    __shared__ float sF[32 * 256];   // 32 KB
    const int t = threadIdx.x;
    const int n0 = blockIdx.x * 32;

    const float4* W4 = (const float4*)W1;
    float4* sW4 = (float4*)sW;
    #pragma unroll
    for (int i = 0; i < 8; ++i) sW4[t + 256 * i] = W4[t + 256 * i];

    const float4* F4 = (const float4*)(feat + (size_t)n0 * 256);
    float4* sF4 = (float4*)sF;
    #pragma unroll
    for (int i = 0; i < 8; ++i) sF4[t + 256 * i] = F4[t + 256 * i];

    __syncthreads();

    const int j = t & 31;
    const int g = t >> 5;
    float acc0 = 0.f, acc1 = 0.f, acc2 = 0.f, acc3 = 0.f;
    const float* f0 = &sF[(g * 4 + 0) * 256];
    const float* f1 = &sF[(g * 4 + 1) * 256];
    const float* f2 = &sF[(g * 4 + 2) * 256];
    const float* f3 = &sF[(g * 4 + 3) * 256];
    #pragma unroll 4
    for (int k = 0; k < 256; ++k) {
        const float w = sW[k * 32 + j];
        acc0 += f0[k] * w;
        acc1 += f1[k] * w;
        acc2 += f2[k] * w;
        acc3 += f3[k] * w;
    }
    const int n = n0 + g * 4;
    h1[(size_t)(n + 0) * 32 + j] = acc0 * nsrc[n + 0];
    h1[(size_t)(n + 1) * 32 + j] = acc1 * nsrc[n + 1];
    h1[(size_t)(n + 2) * 32 + j] = acc2 * nsrc[n + 2];
    h1[(size_t)(n + 3) * 32 + j] = acc3 * nsrc[n + 3];
}

// ---- agg1: x1[n] = relu(ndst[n] * sum_{s in N(n)} h1[s] + b1) -------------
__global__ __launch_bounds__(256) void agg1_kernel(
    const int* __restrict__ csr_src, const int* __restrict__ rowstart,
    const int* __restrict__ indeg, const float* __restrict__ h1,
    const float* __restrict__ ndst, const float* __restrict__ b1,
    float* __restrict__ x1, int N) {
    const int t = threadIdx.x;
    const int n = blockIdx.x * 32 + (t >> 3);
    const int c = t & 7;
    const int rs = rowstart[n];
    const int re = rs + indeg[n];
    float4 acc = {0.f, 0.f, 0.f, 0.f};
    for (int k = rs; k < re; ++k) {
        const int s = csr_src[k];
        const float4 v = *(const float4*)(h1 + (size_t)s * 32 + c * 4);
        acc.x += v.x; acc.y += v.y; acc.z += v.z; acc.w += v.w;
    }
    const float nd = ndst[n];
    const float4 bb = *(const float4*)(b1 + c * 4);
    float4 o;
    o.x = fmaxf(acc.x * nd + bb.x, 0.f);
    o.y = fmaxf(acc.y * nd + bb.y, 0.f);
    o.z = fmaxf(acc.z * nd + bb.z, 0.f);
    o.w = fmaxf(acc.w * nd + bb.w, 0.f);
    *(float4*)(x1 + (size_t)n * 32 + c * 4) = o;
}

// ---- GEMM2: h2[n][j] = nsrc[n] * sum_k x1[n][k] * W2[k][j]   (j<40) ------
__global__ __launch_bounds__(320) void gemm2_kernel(
    const float* __restrict__ x1, const float* __restrict__ W2,
    const float* __restrict__ nsrc, float* __restrict__ h2, int N) {
    __shared__ float sW[32 * 40];
    __shared__ float sX[8 * 32];
    const int t = threadIdx.x;
    const int n0 = blockIdx.x * 8;
    for (int i = t; i < 1280; i += 320) sW[i] = W2[i];
    if (t < 256) sX[t] = x1[(size_t)n0 * 32 + t];
    __syncthreads();
    const int j = t % 40;
    const int ln = t / 40;
    const float* xr = &sX[ln * 32];
    float s = 0.f;
    #pragma unroll
    for (int k = 0; k < 32; ++k) s += xr[k] * sW[k * 40 + j];
    const int n = n0 + ln;
    h2[(size_t)n * 40 + j] = s * nsrc[n];
}

// ---- agg2: agg2[n] = sum_{s in N(n)} h2[s] --------------------------------
__global__ __launch_bounds__(320) void agg2_kernel(
    const int* __restrict__ csr_src, const int* __restrict__ rowstart,
    const int* __restrict__ indeg, const float* __restrict__ h2,
    float* __restrict__ agg2, int N) {
    const int t = threadIdx.x;
    const int n = blockIdx.x * 32 + t / 10;
    const int c = t % 10;
    const int rs = rowstart[n];
    const int re = rs + indeg[n];
    float4 acc = {0.f, 0.f, 0.f, 0.f};
    for (int k = rs; k < re; ++k) {
        const int s = csr_src[k];
        const float4 v = *(const float4*)(h2 + (size_t)s * 40 + c * 4);
        acc.x += v.x; acc.y += v.y; acc.z += v.z; acc.w += v.w;
    }
    *(float4*)(agg2 + (size_t)n * 40 + c * 4) = acc;
}

// ---- final: out = log_softmax(agg2 * ndst + b2), one wave per node --------
__global__ __launch_bounds__(256) void final_kernel(
    const float* __restrict__ agg2, const float* __restrict__ ndst,
    const float* __restrict__ b2, float* __restrict__ out, int N) {
    const int lane = threadIdx.x & 63;
    const int n = blockIdx.x * 4 + (threadIdx.x >> 6);
    if (n >= N) return;
    float v = -INFINITY;
    if (lane < 40) v = agg2[(size_t)n * 40 + lane] * ndst[n] + b2[lane];
    float m = v;
    #pragma unroll
    for (int off = 32; off; off >>= 1) m = fmaxf(m, __shfl_xor(m, off, 64));
    float e = (lane < 40) ? expf(v - m) : 0.f;
    float s = e;
    #pragma unroll
    for (int off = 32; off; off >>= 1) s += __shfl_xor(s, off, 64);
    if (lane < 40) out[(size_t)n * 40 + lane] = v - m - logf(s);
}

extern "C" void kernel_launch(void* const* d_in, const int* in_sizes, int n_in,
                              void* d_out, int out_size, void* d_ws, size_t ws_size,
                              hipStream_t stream) {
    const float* feat = (const float*)d_in[0];
    const int*   src  = (const int*)d_in[1];
    const int*   dst  = (const int*)d_in[2];
    const float* W1   = (const float*)d_in[3];
    const float* b1   = (const float*)d_in[4];
    const float* W2   = (const float*)d_in[5];
    const float* b2   = (const float*)d_in[6];
    float* out = (float*)d_out;

    const int N = in_sizes[0] / 256;   // 100000
    const int E = in_sizes[1];         // 3300000
    const int K = NBUCK(N);            // 391 buckets

    // workspace: 106N floats + (3N + 128 + 400 + E) ints ~= 56.8 MB
    float* nsrc = (float*)d_ws;               // N
    float* ndst = nsrc + N;                   // N
    float* A    = ndst + N;                   // 32N : h1, later agg2 (40N)
    float* B    = A + (size_t)32 * N;         // 32N : x1
    float* C    = B + (size_t)32 * N;         // 40N : h2
    int* outdeg_i = (int*)(C + (size_t)40 * N);  // N
    int* indeg_i  = outdeg_i + N;             // N
    int* rowpos   = indeg_i + N;              // N (exclusive scan = rowstart)
    int* bsum     = rowpos + N;               // 128
    int* gpos     = bsum + 128;               // 400
    int* csr_src  = gpos + 400;               // E

    float* h1   = A;
    float* x1   = B;
    float* h2   = C;
    float* agg2 = A;                   // 40N, overlays dead h1 + 8N of dead x1
    int*   gbuf = (int*)A;             // E ints, overlays A + start of B (dead until gemm1)

    hipMemsetAsync(outdeg_i, 0, sizeof(int) * 2 * (size_t)N, stream);

    const int G = (N + 1023) / 1024;   // 98 blocks for scan1

    hist_kernel<<<(E + 255) / 256, 256, 0, stream>>>(src, dst, outdeg_i, indeg_i, E);
    norm_kernel<<<(N + 255) / 256, 256, 0, stream>>>(outdeg_i, indeg_i, nsrc, ndst, N);
    scan1_kernel<<<G, 256, 0, stream>>>(indeg_i, rowpos, bsum, N);
    scan2_kernel<<<1, 128, 0, stream>>>(bsum, G);
    scan3_kernel<<<(N + 255) / 256, 256, 0, stream>>>(rowpos, bsum, N);
    initgpos_kernel<<<(K + 255) / 256, 256, 0, stream>>>(rowpos, gpos, N, K);
    part_kernel<<<(E + 8191) / 8192, 256, 0, stream>>>(src, dst, gpos, gbuf, E, K);
    fill2_kernel<<<K, 256, 0, stream>>>(rowpos, gbuf, csr_src, N, E, K);

    gemm1_kernel<<<N / 32, 256, 0, stream>>>(feat, W1, nsrc, h1, N);
    agg1_kernel<<<N / 32, 256, 0, stream>>>(csr_src, rowpos, indeg_i, h1, ndst, b1, x1, N);
    gemm2_kernel<<<N / 8, 320, 0, stream>>>(x1, W2, nsrc, h2, N);
    agg2_kernel<<<N / 32, 320, 0, stream>>>(csr_src, rowpos, indeg_i, h2, agg2, N);
    final_kernel<<<(N + 3) / 4, 256, 0, stream>>>(agg2, ndst, b2, out, N);
}

// Round 4
// 574.384 us; speedup vs baseline: 6.8651x; 1.2923x over previous
//
#include <hip/hip_runtime.h>
#include <hip/hip_bf16.h>
#include <math.h>

#define BSHIFT 8                 // 256 nodes per bucket
#define NBUCK(N) (((N) + 255) >> 8)
#define TILE 8192                // edges per partition block

// ---- pass 0: per-tile bucket histograms (dst and src) ---------------------
__global__ __launch_bounds__(256) void bcount_kernel(
    const int* __restrict__ src, const int* __restrict__ dst,
    int* __restrict__ bcntD, int* __restrict__ bcntS, int E, int K) {
    __shared__ int cD[512];
    __shared__ int cS[512];
    const int t = threadIdx.x;
    const int tile = blockIdx.x * TILE;
    for (int i = t; i < 512; i += 256) { cD[i] = 0; cS[i] = 0; }
    __syncthreads();
    #pragma unroll
    for (int i = 0; i < TILE / 256; ++i) {
        const int e = tile + i * 256 + t;
        if (e < E) {
            atomicAdd(&cD[dst[e] >> BSHIFT], 1);
            atomicAdd(&cS[src[e] >> BSHIFT], 1);
        }
    }
    __syncthreads();
    for (int i = t; i < K; i += 256) {
        if (cD[i]) atomicAdd(&bcntD[i], cD[i]);
        if (cS[i]) atomicAdd(&bcntS[i], cS[i]);
    }
}

// ---- pass 1: scan bucket counts -> starts, init cursors (single block) ----
__global__ __launch_bounds__(512) void bscan_kernel(
    const int* __restrict__ bcntD, const int* __restrict__ bcntS,
    int* __restrict__ bstartD, int* __restrict__ bstartS,
    int* __restrict__ gcurD, int* __restrict__ gcurS, int K) {
    __shared__ int s[512];
    const int t = threadIdx.x;
    int v = (t < K) ? bcntD[t] : 0;
    s[t] = v; __syncthreads();
    for (int off = 1; off < 512; off <<= 1) {
        int x = (t >= off) ? s[t - off] : 0;
        __syncthreads(); s[t] += x; __syncthreads();
    }
    if (t < K) { const int e = s[t] - v; bstartD[t] = e; gcurD[t] = e; }
    __syncthreads();
    v = (t < K) ? bcntS[t] : 0;
    s[t] = v; __syncthreads();
    for (int off = 1; off < 512; off <<= 1) {
        int x = (t >= off) ? s[t - off] : 0;
        __syncthreads(); s[t] += x; __syncthreads();
    }
    if (t < K) { const int e = s[t] - v; bstartS[t] = e; gcurS[t] = e; }
}

// ---- pass 2: partition edges into dst-buckets and src-buckets -------------
__global__ __launch_bounds__(256) void part2_kernel(
    const int* __restrict__ src, const int* __restrict__ dst,
    int* __restrict__ gcurD, int* __restrict__ gcurS,
    int* __restrict__ gbufD, unsigned char* __restrict__ gbufS, int E, int K) {
    __shared__ int cD[512];
    __shared__ int bD[512];
    __shared__ int cS[512];
    __shared__ int bS[512];
    const int t = threadIdx.x;
    const int tile = blockIdx.x * TILE;
    for (int i = t; i < 512; i += 256) { cD[i] = 0; cS[i] = 0; }
    __syncthreads();
    #pragma unroll
    for (int i = 0; i < TILE / 256; ++i) {
        const int e = tile + i * 256 + t;
        if (e < E) {
            atomicAdd(&cD[dst[e] >> BSHIFT], 1);
            atomicAdd(&cS[src[e] >> BSHIFT], 1);
        }
    }
    __syncthreads();
    for (int i = t; i < K; i += 256) {
        if (cD[i]) bD[i] = atomicAdd(&gcurD[i], cD[i]);
        cD[i] = 0;
        if (cS[i]) bS[i] = atomicAdd(&gcurS[i], cS[i]);
        cS[i] = 0;
    }
    __syncthreads();
    #pragma unroll
    for (int i = 0; i < TILE / 256; ++i) {
        const int e = tile + i * 256 + t;
        if (e < E) {
            const int dv = dst[e], sv = src[e];
            const int b1 = dv >> BSHIFT;
            const int idx1 = bD[b1] + atomicAdd(&cD[b1], 1);
            gbufD[idx1] = ((dv & 255) << 17) | sv;
            const int b2 = sv >> BSHIFT;
            const int idx2 = bS[b2] + atomicAdd(&cS[b2], 1);
            gbufS[idx2] = (unsigned char)(sv & 255);
        }
    }
}

// ---- pass 3 (dst side): indeg, rowstart, ndst, exact CSR ------------------
// one block per bucket; all scattered writes land in this block's ~34 KB.
__global__ __launch_bounds__(256) void fillD_kernel(
    const int* __restrict__ bstartD, const int* __restrict__ gbufD,
    int* __restrict__ csr_src, int* __restrict__ rowstart, int* __restrict__ indeg,
    float* __restrict__ ndst, int N, int E, int K) {
    __shared__ int cnt[256];
    __shared__ int sc[256];
    __shared__ int cur[256];
    const int t = threadIdx.x;
    const int b = blockIdx.x;
    const int n0 = b << BSHIFT;
    const int bs = bstartD[b];
    const int be = (b == K - 1) ? E : bstartD[b + 1];
    cnt[t] = 0;
    __syncthreads();
    for (int idx = bs + t; idx < be; idx += 256)
        atomicAdd(&cnt[gbufD[idx] >> 17], 1);
    __syncthreads();
    const int deg = cnt[t];
    sc[t] = deg;
    __syncthreads();
    for (int off = 1; off < 256; off <<= 1) {
        int x = (t >= off) ? sc[t - off] : 0;
        __syncthreads(); sc[t] += x; __syncthreads();
    }
    const int rs = bs + sc[t] - deg;
    cur[t] = rs;
    const int n = n0 + t;
    if (n < N) {
        rowstart[n] = rs;
        indeg[n] = deg;
        ndst[n] = rsqrtf((float)deg);   // self-loops => deg >= 1
    }
    __syncthreads();
    for (int idx = bs + t; idx < be; idx += 256) {
        const int p = gbufD[idx];
        const int pos = atomicAdd(&cur[p >> 17], 1);
        csr_src[pos] = p & 131071;
    }
}

// ---- pass 3 (src side): outdeg -> nsrc ------------------------------------
__global__ __launch_bounds__(256) void fillS_kernel(
    const int* __restrict__ bstartS, const unsigned char* __restrict__ gbufS,
    float* __restrict__ nsrc, int N, int E, int K) {
    __shared__ int cnt[256];
    const int t = threadIdx.x;
    const int b = blockIdx.x;
    const int bs = bstartS[b];
    const int be = (b == K - 1) ? E : bstartS[b + 1];
    cnt[t] = 0;
    __syncthreads();
    for (int idx = bs + t; idx < be; idx += 256)
        atomicAdd(&cnt[gbufS[idx]], 1);
    __syncthreads();
    const int n = (b << BSHIFT) + t;
    if (n < N) nsrc[n] = rsqrtf((float)cnt[t]);
}

// ---- GEMM1: h1[n][j] = nsrc[n] * sum_k feat[n][k] * W1[k][j]   (j<32) ----
__global__ __launch_bounds__(256) void gemm1_kernel(
    const float* __restrict__ feat, const float* __restrict__ W1,
    const float* __restrict__ nsrc, float* __restrict__ h1, int N) {
    __shared__ float sW[256 * 32];   // 32 KB
    __shared__ float sF[32 * 256];   // 32 KB
    const int t = threadIdx.x;
    const int n0 = blockIdx.x * 32;

    const float4* W4 = (const float4*)W1;
    float4* sW4 = (float4*)sW;
    #pragma unroll
    for (int i = 0; i < 8; ++i) sW4[t + 256 * i] = W4[t + 256 * i];

    const float4* F4 = (const float4*)(feat + (size_t)n0 * 256);
    float4* sF4 = (float4*)sF;
    #pragma unroll
    for (int i = 0; i < 8; ++i) sF4[t + 256 * i] = F4[t + 256 * i];

    __syncthreads();

    const int j = t & 31;
    const int g = t >> 5;
    float acc0 = 0.f, acc1 = 0.f, acc2 = 0.f, acc3 = 0.f;
    const float* f0 = &sF[(g * 4 + 0) * 256];
    const float* f1 = &sF[(g * 4 + 1) * 256];
    const float* f2 = &sF[(g * 4 + 2) * 256];
    const float* f3 = &sF[(g * 4 + 3) * 256];
    #pragma unroll 4
    for (int k = 0; k < 256; ++k) {
        const float w = sW[k * 32 + j];
        acc0 += f0[k] * w;
        acc1 += f1[k] * w;
        acc2 += f2[k] * w;
        acc3 += f3[k] * w;
    }
    const int n = n0 + g * 4;
    h1[(size_t)(n + 0) * 32 + j] = acc0 * nsrc[n + 0];
    h1[(size_t)(n + 1) * 32 + j] = acc1 * nsrc[n + 1];
    h1[(size_t)(n + 2) * 32 + j] = acc2 * nsrc[n + 2];
    h1[(size_t)(n + 3) * 32 + j] = acc3 * nsrc[n + 3];
}

// ---- agg1: x1[n] = relu(ndst[n] * sum_{s in N(n)} h1[s] + b1) -------------
__global__ __launch_bounds__(256) void agg1_kernel(
    const int* __restrict__ csr_src, const int* __restrict__ rowstart,
    const int* __restrict__ indeg, const float* __restrict__ h1,
    const float* __restrict__ ndst, const float* __restrict__ b1,
    float* __restrict__ x1, int N) {
    const int t = threadIdx.x;
    const int n = blockIdx.x * 32 + (t >> 3);
    const int c = t & 7;
    const int rs = rowstart[n];
    const int re = rs + indeg[n];
    float4 acc = {0.f, 0.f, 0.f, 0.f};
    for (int k = rs; k < re; ++k) {
        const int s = csr_src[k];
        const float4 v = *(const float4*)(h1 + (size_t)s * 32 + c * 4);
        acc.x += v.x; acc.y += v.y; acc.z += v.z; acc.w += v.w;
    }
    const float nd = ndst[n];
    const float4 bb = *(const float4*)(b1 + c * 4);
    float4 o;
    o.x = fmaxf(acc.x * nd + bb.x, 0.f);
    o.y = fmaxf(acc.y * nd + bb.y, 0.f);
    o.z = fmaxf(acc.z * nd + bb.z, 0.f);
    o.w = fmaxf(acc.w * nd + bb.w, 0.f);
    *(float4*)(x1 + (size_t)n * 32 + c * 4) = o;
}

// ---- GEMM2: h2[n][j] = nsrc[n] * sum_k x1[n][k] * W2[k][j]   (j<40) ------
__global__ __launch_bounds__(320) void gemm2_kernel(
    const float* __restrict__ x1, const float* __restrict__ W2,
    const float* __restrict__ nsrc, float* __restrict__ h2, int N) {
    __shared__ float sW[32 * 40];
    __shared__ float sX[8 * 32];
    const int t = threadIdx.x;
    const int n0 = blockIdx.x * 8;
    for (int i = t; i < 1280; i += 320) sW[i] = W2[i];
    if (t < 256) sX[t] = x1[(size_t)n0 * 32 + t];
    __syncthreads();
    const int j = t % 40;
    const int ln = t / 40;
    const float* xr = &sX[ln * 32];
    float s = 0.f;
    #pragma unroll
    for (int k = 0; k < 32; ++k) s += xr[k] * sW[k * 40 + j];
    const int n = n0 + ln;
    h2[(size_t)n * 40 + j] = s * nsrc[n];
}

// ---- agg2: agg2[n] = sum_{s in N(n)} h2[s] --------------------------------
__global__ __launch_bounds__(320) void agg2_kernel(
    const int* __restrict__ csr_src, const int* __restrict__ rowstart,
    const int* __restrict__ indeg, const float* __restrict__ h2,
    float* __restrict__ agg2, int N) {
    const int t = threadIdx.x;
    const int n = blockIdx.x * 32 + t / 10;
    const int c = t % 10;
    const int rs = rowstart[n];
    const int re = rs + indeg[n];
    float4 acc = {0.f, 0.f, 0.f, 0.f};
    for (int k = rs; k < re; ++k) {
        const int s = csr_src[k];
        const float4 v = *(const float4*)(h2 + (size_t)s * 40 + c * 4);
        acc.x += v.x; acc.y += v.y; acc.z += v.z; acc.w += v.w;
    }
    *(float4*)(agg2 + (size_t)n * 40 + c * 4) = acc;
}

// ---- final: out = log_softmax(agg2 * ndst + b2), one wave per node --------
__global__ __launch_bounds__(256) void final_kernel(
    const float* __restrict__ agg2, const float* __restrict__ ndst,
    const float* __restrict__ b2, float* __restrict__ out, int N) {
    const int lane = threadIdx.x & 63;
    const int n = blockIdx.x * 4 + (threadIdx.x >> 6);
    if (n >= N) return;
    float v = -INFINITY;
    if (lane < 40) v = agg2[(size_t)n * 40 + lane] * ndst[n] + b2[lane];
    float m = v;
    #pragma unroll
    for (int off = 32; off; off >>= 1) m = fmaxf(m, __shfl_xor(m, off, 64));
    float e = (lane < 40) ? expf(v - m) : 0.f;
    float s = e;
    #pragma unroll
    for (int off = 32; off; off >>= 1) s += __shfl_xor(s, off, 64);
    if (lane < 40) out[(size_t)n * 40 + lane] = v - m - logf(s);
}

extern "C" void kernel_launch(void* const* d_in, const int* in_sizes, int n_in,
                              void* d_out, int out_size, void* d_ws, size_t ws_size,
                              hipStream_t stream) {
    const float* feat = (const float*)d_in[0];
    const int*   src  = (const int*)d_in[1];
    const int*   dst  = (const int*)d_in[2];
    const float* W1   = (const float*)d_in[3];
    const float* b1   = (const float*)d_in[4];
    const float* W2   = (const float*)d_in[5];
    const float* b2   = (const float*)d_in[6];
    float* out = (float*)d_out;

    const int N = in_sizes[0] / 256;   // 100000
    const int E = in_sizes[1];         // 3300000
    const int K = NBUCK(N);            // 391 buckets

    // persistent float region: nsrc,ndst + A(32N) + B(32N) + C(40N) = 106N floats
    float* nsrc = (float*)d_ws;               // N
    float* ndst = nsrc + N;                   // N
    float* A    = ndst + N;                   // 32N : h1, later agg2 (40N)
    float* B    = A + (size_t)32 * N;         // 32N : x1
    float* C    = B + (size_t)32 * N;         // 40N : h2
    // persistent int region after floats:
    int* rowstart = (int*)(C + (size_t)40 * N);  // N
    int* indeg_i  = rowstart + N;             // N
    int* bcntD    = indeg_i + N;              // 512
    int* bcntS    = bcntD + 512;              // 512
    int* bstartD  = bcntS + 512;              // 512
    int* bstartS  = bstartD + 512;            // 512
    int* gcurD    = bstartS + 512;            // 512
    int* gcurS    = gcurD + 512;              // 512
    int* csr_src  = gcurS + 512;              // E
    // transient overlays (dead float regions during CSR build):
    int* gbufD = (int*)A;                     // E ints (13.2 MB over A + start of B)
    unsigned char* gbufS = (unsigned char*)C; // E bytes (3.3 MB over C)

    float* h1   = A;
    float* x1   = B;
    float* h2   = C;
    float* agg2 = A;   // 40N, overlays dead h1 + 8N of dead x1

    hipMemsetAsync(bcntD, 0, sizeof(int) * 1024, stream);  // bcntD + bcntS

    const int PB = (E + TILE - 1) / TILE;   // 403 partition blocks

    bcount_kernel<<<PB, 256, 0, stream>>>(src, dst, bcntD, bcntS, E, K);
    bscan_kernel<<<1, 512, 0, stream>>>(bcntD, bcntS, bstartD, bstartS, gcurD, gcurS, K);
    part2_kernel<<<PB, 256, 0, stream>>>(src, dst, gcurD, gcurS, gbufD, gbufS, E, K);
    fillD_kernel<<<K, 256, 0, stream>>>(bstartD, gbufD, csr_src, rowstart, indeg_i, ndst, N, E, K);
    fillS_kernel<<<K, 256, 0, stream>>>(bstartS, gbufS, nsrc, N, E, K);

    gemm1_kernel<<<N / 32, 256, 0, stream>>>(feat, W1, nsrc, h1, N);
    agg1_kernel<<<N / 32, 256, 0, stream>>>(csr_src, rowstart, indeg_i, h1, ndst, b1, x1, N);
    gemm2_kernel<<<N / 8, 320, 0, stream>>>(x1, W2, nsrc, h2, N);
    agg2_kernel<<<N / 32, 320, 0, stream>>>(csr_src, rowstart, indeg_i, h2, agg2, N);
    final_kernel<<<(N + 3) / 4, 256, 0, stream>>>(agg2, ndst, b2, out, N);
}

// Round 7
// 530.217 us; speedup vs baseline: 7.4370x; 1.0833x over previous
//
#include <hip/hip_runtime.h>
#include <hip/hip_bf16.h>
#include <math.h>

#define BSHIFT 8                 // 256 nodes per bucket
#define NBUCK(N) (((N) + 255) >> 8)
#define TILE 8192                // edges per partition block

// ---- bf16 helpers ---------------------------------------------------------
__device__ __forceinline__ unsigned short f2bf(float f) {
    unsigned u = __float_as_uint(f);
    u += 0x7fffu + ((u >> 16) & 1u);      // RNE
    return (unsigned short)(u >> 16);
}
__device__ __forceinline__ unsigned packbf2(float lo, float hi) {
    return (unsigned)f2bf(lo) | ((unsigned)f2bf(hi) << 16);
}
__device__ __forceinline__ float bf_lo(unsigned u) { return __uint_as_float(u << 16); }
__device__ __forceinline__ float bf_hi(unsigned u) { return __uint_as_float(u & 0xffff0000u); }

// ---- pass 0: per-tile bucket histograms (dst and src) ---------------------
__global__ __launch_bounds__(256) void bcount_kernel(
    const int* __restrict__ src, const int* __restrict__ dst,
    int* __restrict__ bcntD, int* __restrict__ bcntS, int E, int K) {
    __shared__ int cD[512];
    __shared__ int cS[512];
    const int t = threadIdx.x;
    const int tile = blockIdx.x * TILE;
    for (int i = t; i < 512; i += 256) { cD[i] = 0; cS[i] = 0; }
    __syncthreads();
    #pragma unroll
    for (int i = 0; i < TILE / 256; ++i) {
        const int e = tile + i * 256 + t;
        if (e < E) {
            atomicAdd(&cD[dst[e] >> BSHIFT], 1);
            atomicAdd(&cS[src[e] >> BSHIFT], 1);
        }
    }
    __syncthreads();
    for (int i = t; i < K; i += 256) {
        if (cD[i]) atomicAdd(&bcntD[i], cD[i]);
        if (cS[i]) atomicAdd(&bcntS[i], cS[i]);
    }
}

// ---- pass 1: scan bucket counts -> starts, init cursors (single block) ----
__global__ __launch_bounds__(512) void bscan_kernel(
    const int* __restrict__ bcntD, const int* __restrict__ bcntS,
    int* __restrict__ bstartD, int* __restrict__ bstartS,
    int* __restrict__ gcurD, int* __restrict__ gcurS, int K) {
    __shared__ int s[512];
    const int t = threadIdx.x;
    int v = (t < K) ? bcntD[t] : 0;
    s[t] = v; __syncthreads();
    for (int off = 1; off < 512; off <<= 1) {
        int x = (t >= off) ? s[t - off] : 0;
        __syncthreads(); s[t] += x; __syncthreads();
    }
    if (t < K) { const int e = s[t] - v; bstartD[t] = e; gcurD[t] = e; }
    __syncthreads();
    v = (t < K) ? bcntS[t] : 0;
    s[t] = v; __syncthreads();
    for (int off = 1; off < 512; off <<= 1) {
        int x = (t >= off) ? s[t - off] : 0;
        __syncthreads(); s[t] += x; __syncthreads();
    }
    if (t < K) { const int e = s[t] - v; bstartS[t] = e; gcurS[t] = e; }
}

// ---- pass 2: partition edges into dst-buckets and src-buckets -------------
__global__ __launch_bounds__(256) void part2_kernel(
    const int* __restrict__ src, const int* __restrict__ dst,
    int* __restrict__ gcurD, int* __restrict__ gcurS,
    int* __restrict__ gbufD, unsigned char* __restrict__ gbufS, int E, int K) {
    __shared__ int cD[512];
    __shared__ int bD[512];
    __shared__ int cS[512];
    __shared__ int bS[512];
    const int t = threadIdx.x;
    const int tile = blockIdx.x * TILE;
    for (int i = t; i < 512; i += 256) { cD[i] = 0; cS[i] = 0; }
    __syncthreads();
    #pragma unroll
    for (int i = 0; i < TILE / 256; ++i) {
        const int e = tile + i * 256 + t;
        if (e < E) {
            atomicAdd(&cD[dst[e] >> BSHIFT], 1);
            atomicAdd(&cS[src[e] >> BSHIFT], 1);
        }
    }
    __syncthreads();
    for (int i = t; i < K; i += 256) {
        if (cD[i]) bD[i] = atomicAdd(&gcurD[i], cD[i]);
        cD[i] = 0;
        if (cS[i]) bS[i] = atomicAdd(&gcurS[i], cS[i]);
        cS[i] = 0;
    }
    __syncthreads();
    #pragma unroll
    for (int i = 0; i < TILE / 256; ++i) {
        const int e = tile + i * 256 + t;
        if (e < E) {
            const int dv = dst[e], sv = src[e];
            const int b1 = dv >> BSHIFT;
            const int idx1 = bD[b1] + atomicAdd(&cD[b1], 1);
            gbufD[idx1] = ((dv & 255) << 17) | sv;
            const int b2 = sv >> BSHIFT;
            const int idx2 = bS[b2] + atomicAdd(&cS[b2], 1);
            gbufS[idx2] = (unsigned char)(sv & 255);
        }
    }
}

// ---- pass 3 (dst side): indeg, rowstart, ndst, exact CSR ------------------
__global__ __launch_bounds__(256) void fillD_kernel(
    const int* __restrict__ bstartD, const int* __restrict__ gbufD,
    int* __restrict__ csr_src, int* __restrict__ rowstart, int* __restrict__ indeg,
    float* __restrict__ ndst, int N, int E, int K) {
    __shared__ int cnt[256];
    __shared__ int sc[256];
    __shared__ int cur[256];
    const int t = threadIdx.x;
    const int b = blockIdx.x;
    const int n0 = b << BSHIFT;
    const int bs = bstartD[b];
    const int be = (b == K - 1) ? E : bstartD[b + 1];
    cnt[t] = 0;
    __syncthreads();
    for (int idx = bs + t; idx < be; idx += 256)
        atomicAdd(&cnt[gbufD[idx] >> 17], 1);
    __syncthreads();
    const int deg = cnt[t];
    sc[t] = deg;
    __syncthreads();
    for (int off = 1; off < 256; off <<= 1) {
        int x = (t >= off) ? sc[t - off] : 0;
        __syncthreads(); sc[t] += x; __syncthreads();
    }
    const int rs = bs + sc[t] - deg;
    cur[t] = rs;
    const int n = n0 + t;
    if (n < N) {
        rowstart[n] = rs;
        indeg[n] = deg;
        ndst[n] = rsqrtf((float)deg);   // self-loops => deg >= 1
    }
    __syncthreads();
    for (int idx = bs + t; idx < be; idx += 256) {
        const int p = gbufD[idx];
        const int pos = atomicAdd(&cur[p >> 17], 1);
        csr_src[pos] = p & 131071;
    }
}

// ---- pass 3 (src side): outdeg -> nsrc ------------------------------------
__global__ __launch_bounds__(256) void fillS_kernel(
    const int* __restrict__ bstartS, const unsigned char* __restrict__ gbufS,
    float* __restrict__ nsrc, int N, int E, int K) {
    __shared__ int cnt[256];
    const int t = threadIdx.x;
    const int b = blockIdx.x;
    const int bs = bstartS[b];
    const int be = (b == K - 1) ? E : bstartS[b + 1];
    cnt[t] = 0;
    __syncthreads();
    for (int idx = bs + t; idx < be; idx += 256)
        atomicAdd(&cnt[gbufS[idx]], 1);
    __syncthreads();
    const int n = (b << BSHIFT) + t;
    if (n < N) nsrc[n] = rsqrtf((float)cnt[t]);
}

// ---- GEMM1: h1[n][j] = bf16( nsrc[n] * sum_k feat[n][k] * W1[k][j] ) ------
// thread = 1 node x 4 cols. sF XOR-swizzled: elem (r,c) at r*256 + (c ^ 4r).
// 64 KB static LDS total (proven to launch in rounds 2-4).
// NOTE: h1 row = 32 bf16 = 16 uints — stride 16 (stride-8 bug caused the
// round 5/6 NaNs: upper half of h1 kept the stale gbufD overlay whose packed
// ints decode to bf16 NaN).
__global__ __launch_bounds__(256) void gemm1_kernel(
    const float* __restrict__ feat, const float* __restrict__ W1,
    const float* __restrict__ nsrc, unsigned* __restrict__ h1, int N) {
    __shared__ float sW[256 * 32];        // 32 KB
    __shared__ float sF[32 * 256];        // 32 KB, XOR swizzle
    const int t = threadIdx.x;
    const int n0 = blockIdx.x * 32;

    const float4* W4 = (const float4*)W1;
    float4* sW4 = (float4*)sW;
    #pragma unroll
    for (int i = 0; i < 8; ++i) sW4[t + 256 * i] = W4[t + 256 * i];

    const float4* F4 = (const float4*)(feat + (size_t)n0 * 256);
    #pragma unroll
    for (int i = 0; i < 8; ++i) {
        const int idx = t + 256 * i;
        const int r = idx >> 6, c4 = (idx & 63) << 2;
        // swizzle value (4r, mult of 4) preserves float4 contiguity/alignment
        *(float4*)&sF[r * 256 + (c4 ^ ((r << 2) & 255))] = F4[idx];
    }
    __syncthreads();

    const int g  = t >> 3;                // node in block (0..31)
    const int j4 = (t & 7) << 2;          // col group (0,4,..,28)
    const int sw = (g << 2) & 255;        // per-row swizzle
    float4 acc = {0.f, 0.f, 0.f, 0.f};
    const float* fr = &sF[g * 256];
    #pragma unroll 4
    for (int k = 0; k < 256; ++k) {
        const float4 w = *(const float4*)&sW[k * 32 + j4];
        const float f = fr[k ^ sw];
        acc.x += f * w.x; acc.y += f * w.y; acc.z += f * w.z; acc.w += f * w.w;
    }
    const int n = n0 + g;
    const float s = nsrc[n];
    uint2 o;
    o.x = packbf2(acc.x * s, acc.y * s);
    o.y = packbf2(acc.z * s, acc.w * s);
    *(uint2*)&h1[(size_t)n * 16 + (j4 >> 1)] = o;   // row stride = 16 uints
}

// ---- agg1: x1s[n] = bf16( relu(ndst[n]*sum h1[src] + b1) * nsrc[n] ) ------
// 64 nodes/block, 4 lanes/node, 16 B bf16x8 per lane per edge.
__global__ __launch_bounds__(256) void agg1_kernel(
    const int* __restrict__ csr_src, const int* __restrict__ rowstart,
    const int* __restrict__ indeg, const unsigned* __restrict__ h1,
    const float* __restrict__ ndst, const float* __restrict__ nsrc,
    const float* __restrict__ b1, unsigned* __restrict__ x1s, int N) {
    const int t = threadIdx.x;
    const int n = blockIdx.x * 64 + (t >> 2);
    if (n >= N) return;
    const int c = t & 3;
    const int rs = rowstart[n];
    const int re = rs + indeg[n];
    float a0=0.f,a1=0.f,a2=0.f,a3=0.f,a4=0.f,a5=0.f,a6=0.f,a7=0.f;
    const uint4* H = (const uint4*)h1;    // 4 uint4 per row
    for (int k = rs; k < re; ++k) {
        const int s = csr_src[k];
        const uint4 q = H[(size_t)s * 4 + c];
        a0 += bf_lo(q.x); a1 += bf_hi(q.x);
        a2 += bf_lo(q.y); a3 += bf_hi(q.y);
        a4 += bf_lo(q.z); a5 += bf_hi(q.z);
        a6 += bf_lo(q.w); a7 += bf_hi(q.w);
    }
    const float nd = ndst[n];
    const float ns = nsrc[n];
    const float* bb = b1 + c * 8;
    float x0 = fmaxf(a0 * nd + bb[0], 0.f) * ns;
    float x1 = fmaxf(a1 * nd + bb[1], 0.f) * ns;
    float x2 = fmaxf(a2 * nd + bb[2], 0.f) * ns;
    float x3 = fmaxf(a3 * nd + bb[3], 0.f) * ns;
    float x4 = fmaxf(a4 * nd + bb[4], 0.f) * ns;
    float x5 = fmaxf(a5 * nd + bb[5], 0.f) * ns;
    float x6 = fmaxf(a6 * nd + bb[6], 0.f) * ns;
    float x7 = fmaxf(a7 * nd + bb[7], 0.f) * ns;
    uint4 o;
    o.x = packbf2(x0, x1); o.y = packbf2(x2, x3);
    o.z = packbf2(x4, x5); o.w = packbf2(x6, x7);
    ((uint4*)x1s)[(size_t)n * 4 + c] = o;
}

// ---- agg2: a2[n] = ndst[n] * sum x1s[src]   (fp32 out, 32-wide) -----------
__global__ __launch_bounds__(256) void agg2_kernel(
    const int* __restrict__ csr_src, const int* __restrict__ rowstart,
    const int* __restrict__ indeg, const unsigned* __restrict__ x1s,
    const float* __restrict__ ndst, float* __restrict__ a2out, int N) {
    const int t = threadIdx.x;
    const int n = blockIdx.x * 64 + (t >> 2);
    if (n >= N) return;
    const int c = t & 3;
    const int rs = rowstart[n];
    const int re = rs + indeg[n];
    float a0=0.f,a1=0.f,a2=0.f,a3=0.f,a4=0.f,a5=0.f,a6=0.f,a7=0.f;
    const uint4* H = (const uint4*)x1s;
    for (int k = rs; k < re; ++k) {
        const int s = csr_src[k];
        const uint4 q = H[(size_t)s * 4 + c];
        a0 += bf_lo(q.x); a1 += bf_hi(q.x);
        a2 += bf_lo(q.y); a3 += bf_hi(q.y);
        a4 += bf_lo(q.z); a5 += bf_hi(q.z);
        a6 += bf_lo(q.w); a7 += bf_hi(q.w);
    }
    const float nd = ndst[n];
    float4 o0 = {a0 * nd, a1 * nd, a2 * nd, a3 * nd};
    float4 o1 = {a4 * nd, a5 * nd, a6 * nd, a7 * nd};
    *(float4*)&a2out[(size_t)n * 32 + c * 8] = o0;
    *(float4*)&a2out[(size_t)n * 32 + c * 8 + 4] = o1;
}

// ---- final: out = log_softmax(a2 @ W2 + b2), one wave per node ------------
__global__ __launch_bounds__(256) void final_kernel(
    const float* __restrict__ a2, const float* __restrict__ W2,
    const float* __restrict__ b2, float* __restrict__ out, int N) {
    __shared__ float sW2[32 * 40];
    __shared__ float sb2[40];
    const int t = threadIdx.x;
    for (int i = t; i < 1280; i += 256) sW2[i] = W2[i];
    if (t < 40) sb2[t] = b2[t];
    __syncthreads();
    const int lane = t & 63;
    const int n = blockIdx.x * 4 + (t >> 6);
    if (n >= N) return;
    const float v = a2[(size_t)n * 32 + (lane & 31)];
    const int jj = (lane < 40) ? lane : 39;
    float z = sb2[jj];
    #pragma unroll
    for (int k = 0; k < 32; ++k) {
        const float ak = __shfl(v, k, 64);
        z += ak * sW2[k * 40 + jj];
    }
    if (lane >= 40) z = -INFINITY;
    float m = z;
    #pragma unroll
    for (int off = 32; off; off >>= 1) m = fmaxf(m, __shfl_xor(m, off, 64));
    float e = (lane < 40) ? __expf(z - m) : 0.f;
    float s = e;
    #pragma unroll
    for (int off = 32; off; off >>= 1) s += __shfl_xor(s, off, 64);
    if (lane < 40) out[(size_t)n * 40 + lane] = z - m - __logf(s);
}

extern "C" void kernel_launch(void* const* d_in, const int* in_sizes, int n_in,
                              void* d_out, int out_size, void* d_ws, size_t ws_size,
                              hipStream_t stream) {
    const float* feat = (const float*)d_in[0];
    const int*   src  = (const int*)d_in[1];
    const int*   dst  = (const int*)d_in[2];
    const float* W1   = (const float*)d_in[3];
    const float* b1   = (const float*)d_in[4];
    const float* W2   = (const float*)d_in[5];
    const float* b2   = (const float*)d_in[6];
    float* out = (float*)d_out;

    const int N = in_sizes[0] / 256;   // 100000
    const int E = in_sizes[1];         // 3300000
    const int K = NBUCK(N);            // 391 buckets

    // layout (bytes): nsrc/ndst fp32, h1/x1s bf16 (64 B rows), a2 fp32, ints.
    char* p = (char*)d_ws;
    float* nsrc = (float*)p;                 p += (size_t)N * 4;        // 400 KB
    float* ndst = (float*)p;                 p += (size_t)N * 4;
    unsigned* h1  = (unsigned*)p;            p += (size_t)N * 64;       // 6.4 MB
    unsigned* x1s = (unsigned*)p;            p += (size_t)N * 64;       // 6.4 MB
    float* a2 = (float*)p;                   p += (size_t)N * 128;      // 12.8 MB
    int* rowstart = (int*)p;                 p += (size_t)N * 4;
    int* indeg_i  = (int*)p;                 p += (size_t)N * 4;
    int* bcntD    = (int*)p;                 p += 512 * 4;
    int* bcntS    = (int*)p;                 p += 512 * 4;
    int* bstartD  = (int*)p;                 p += 512 * 4;
    int* bstartS  = (int*)p;                 p += 512 * 4;
    int* gcurD    = (int*)p;                 p += 512 * 4;
    int* gcurS    = (int*)p;                 p += 512 * 4;
    int* csr_src  = (int*)p;                 p += (size_t)E * 4;        // 13.2 MB
    // transient overlays over [h1, x1s, a2] (dead during CSR build):
    int* gbufD = (int*)h1;                              // E ints  = 13.2 MB
    unsigned char* gbufS = (unsigned char*)h1 + (size_t)E * 4;  // E bytes = 3.3 MB

    hipMemsetAsync(bcntD, 0, sizeof(int) * 1024, stream);  // bcntD + bcntS

    const int PB = (E + TILE - 1) / TILE;

    bcount_kernel<<<PB, 256, 0, stream>>>(src, dst, bcntD, bcntS, E, K);
    bscan_kernel<<<1, 512, 0, stream>>>(bcntD, bcntS, bstartD, bstartS, gcurD, gcurS, K);
    part2_kernel<<<PB, 256, 0, stream>>>(src, dst, gcurD, gcurS, gbufD, gbufS, E, K);
    fillD_kernel<<<K, 256, 0, stream>>>(bstartD, gbufD, csr_src, rowstart, indeg_i, ndst, N, E, K);
    fillS_kernel<<<K, 256, 0, stream>>>(bstartS, gbufS, nsrc, N, E, K);

    gemm1_kernel<<<N / 32, 256, 0, stream>>>(feat, W1, nsrc, h1, N);
    agg1_kernel<<<(N + 63) / 64, 256, 0, stream>>>(csr_src, rowstart, indeg_i, h1, ndst, nsrc, b1, x1s, N);
    agg2_kernel<<<(N + 63) / 64, 256, 0, stream>>>(csr_src, rowstart, indeg_i, x1s, ndst, a2, N);
    final_kernel<<<(N + 3) / 4, 256, 0, stream>>>(a2, W2, b2, out, N);
}

// Round 8
// 514.040 us; speedup vs baseline: 7.6710x; 1.0315x over previous
//
#include <hip/hip_runtime.h>
#include <hip/hip_bf16.h>
#include <math.h>

#define BSHIFT 8                 // 256 nodes per bucket
#define NBUCK(N) (((N) + 255) >> 8)
#define TILE 8192                // edges per partition block

typedef short bf16x8 __attribute__((ext_vector_type(8)));
typedef float f32x16 __attribute__((ext_vector_type(16)));

// ---- bf16 helpers ---------------------------------------------------------
__device__ __forceinline__ unsigned short f2bf(float f) {
    unsigned u = __float_as_uint(f);
    u += 0x7fffu + ((u >> 16) & 1u);      // RNE
    return (unsigned short)(u >> 16);
}
__device__ __forceinline__ unsigned packbf2(float lo, float hi) {
    return (unsigned)f2bf(lo) | ((unsigned)f2bf(hi) << 16);
}
__device__ __forceinline__ float bf_lo(unsigned u) { return __uint_as_float(u << 16); }
__device__ __forceinline__ float bf_hi(unsigned u) { return __uint_as_float(u & 0xffff0000u); }

// ---- pass 0: per-tile bucket histograms (dst and src) ---------------------
__global__ __launch_bounds__(256) void bcount_kernel(
    const int* __restrict__ src, const int* __restrict__ dst,
    int* __restrict__ bcntD, int* __restrict__ bcntS, int E, int K) {
    __shared__ int cD[512];
    __shared__ int cS[512];
    const int t = threadIdx.x;
    const int tile = blockIdx.x * TILE;
    for (int i = t; i < 512; i += 256) { cD[i] = 0; cS[i] = 0; }
    __syncthreads();
    #pragma unroll
    for (int i = 0; i < TILE / 256; ++i) {
        const int e = tile + i * 256 + t;
        if (e < E) {
            atomicAdd(&cD[dst[e] >> BSHIFT], 1);
            atomicAdd(&cS[src[e] >> BSHIFT], 1);
        }
    }
    __syncthreads();
    for (int i = t; i < K; i += 256) {
        if (cD[i]) atomicAdd(&bcntD[i], cD[i]);
        if (cS[i]) atomicAdd(&bcntS[i], cS[i]);
    }
}

// ---- pass 1: scan bucket counts -> starts, init cursors (single block) ----
__global__ __launch_bounds__(512) void bscan_kernel(
    const int* __restrict__ bcntD, const int* __restrict__ bcntS,
    int* __restrict__ bstartD, int* __restrict__ bstartS,
    int* __restrict__ gcurD, int* __restrict__ gcurS, int K) {
    __shared__ int s[512];
    const int t = threadIdx.x;
    int v = (t < K) ? bcntD[t] : 0;
    s[t] = v; __syncthreads();
    for (int off = 1; off < 512; off <<= 1) {
        int x = (t >= off) ? s[t - off] : 0;
        __syncthreads(); s[t] += x; __syncthreads();
    }
    if (t < K) { const int e = s[t] - v; bstartD[t] = e; gcurD[t] = e; }
    __syncthreads();
    v = (t < K) ? bcntS[t] : 0;
    s[t] = v; __syncthreads();
    for (int off = 1; off < 512; off <<= 1) {
        int x = (t >= off) ? s[t - off] : 0;
        __syncthreads(); s[t] += x; __syncthreads();
    }
    if (t < K) { const int e = s[t] - v; bstartS[t] = e; gcurS[t] = e; }
}

// ---- pass 2: partition edges into dst-buckets and src-buckets -------------
__global__ __launch_bounds__(256) void part2_kernel(
    const int* __restrict__ src, const int* __restrict__ dst,
    int* __restrict__ gcurD, int* __restrict__ gcurS,
    int* __restrict__ gbufD, unsigned char* __restrict__ gbufS, int E, int K) {
    __shared__ int cD[512];
    __shared__ int bD[512];
    __shared__ int cS[512];
    __shared__ int bS[512];
    const int t = threadIdx.x;
    const int tile = blockIdx.x * TILE;
    for (int i = t; i < 512; i += 256) { cD[i] = 0; cS[i] = 0; }
    __syncthreads();
    #pragma unroll
    for (int i = 0; i < TILE / 256; ++i) {
        const int e = tile + i * 256 + t;
        if (e < E) {
            atomicAdd(&cD[dst[e] >> BSHIFT], 1);
            atomicAdd(&cS[src[e] >> BSHIFT], 1);
        }
    }
    __syncthreads();
    for (int i = t; i < K; i += 256) {
        if (cD[i]) bD[i] = atomicAdd(&gcurD[i], cD[i]);
        cD[i] = 0;
        if (cS[i]) bS[i] = atomicAdd(&gcurS[i], cS[i]);
        cS[i] = 0;
    }
    __syncthreads();
    #pragma unroll
    for (int i = 0; i < TILE / 256; ++i) {
        const int e = tile + i * 256 + t;
        if (e < E) {
            const int dv = dst[e], sv = src[e];
            const int b1 = dv >> BSHIFT;
            const int idx1 = bD[b1] + atomicAdd(&cD[b1], 1);
            gbufD[idx1] = ((dv & 255) << 17) | sv;
            const int b2 = sv >> BSHIFT;
            const int idx2 = bS[b2] + atomicAdd(&cS[b2], 1);
            gbufS[idx2] = (unsigned char)(sv & 255);
        }
    }
}

// ---- pass 3 (dst side): indeg, rowstart, ndst, exact CSR ------------------
__global__ __launch_bounds__(256) void fillD_kernel(
    const int* __restrict__ bstartD, const int* __restrict__ gbufD,
    int* __restrict__ csr_src, int* __restrict__ rowstart, int* __restrict__ indeg,
    float* __restrict__ ndst, int N, int E, int K) {
    __shared__ int cnt[256];
    __shared__ int sc[256];
    __shared__ int cur[256];
    const int t = threadIdx.x;
    const int b = blockIdx.x;
    const int n0 = b << BSHIFT;
    const int bs = bstartD[b];
    const int be = (b == K - 1) ? E : bstartD[b + 1];
    cnt[t] = 0;
    __syncthreads();
    for (int idx = bs + t; idx < be; idx += 256)
        atomicAdd(&cnt[gbufD[idx] >> 17], 1);
    __syncthreads();
    const int deg = cnt[t];
    sc[t] = deg;
    __syncthreads();
    for (int off = 1; off < 256; off <<= 1) {
        int x = (t >= off) ? sc[t - off] : 0;
        __syncthreads(); sc[t] += x; __syncthreads();
    }
    const int rs = bs + sc[t] - deg;
    cur[t] = rs;
    const int n = n0 + t;
    if (n < N) {
        rowstart[n] = rs;
        indeg[n] = deg;
        ndst[n] = rsqrtf((float)deg);   // self-loops => deg >= 1
    }
    __syncthreads();
    for (int idx = bs + t; idx < be; idx += 256) {
        const int p = gbufD[idx];
        const int pos = atomicAdd(&cur[p >> 17], 1);
        csr_src[pos] = p & 131071;
    }
}

// ---- pass 3 (src side): outdeg -> nsrc ------------------------------------
__global__ __launch_bounds__(256) void fillS_kernel(
    const int* __restrict__ bstartS, const unsigned char* __restrict__ gbufS,
    float* __restrict__ nsrc, int N, int E, int K) {
    __shared__ int cnt[256];
    const int t = threadIdx.x;
    const int b = blockIdx.x;
    const int bs = bstartS[b];
    const int be = (b == K - 1) ? E : bstartS[b + 1];
    cnt[t] = 0;
    __syncthreads();
    for (int idx = bs + t; idx < be; idx += 256)
        atomicAdd(&cnt[gbufS[idx]], 1);
    __syncthreads();
    const int n = (b << BSHIFT) + t;
    if (n < N) nsrc[n] = rsqrtf((float)cnt[t]);
}

// ---- GEMM1 (MFMA): h1[n][j] = bf16( nsrc[n] * sum_k feat[n][k]*W1[k][j] ) -
// 4 waves/block, 32 nodes/wave (128 nodes/block). v_mfma_f32_32x32x16_bf16,
// K-loop of 16. A-frags straight from global (no LDS staging); B = W1
// transposed to bf16 in LDS, padded rows (264) for ds_read_b128.
// Fragment maps (cdna4_isa/guide): A: lane l holds A[l&31][8*(l>>5)+j];
// B: lane l holds B[8*(l>>5)+j][l&31]; D: col=lane&31,
// row=(reg&3)+8*(reg>>2)+4*(lane>>5).
__global__ __launch_bounds__(256) void gemm1_kernel(
    const float* __restrict__ feat, const float* __restrict__ W1,
    const float* __restrict__ nsrc, unsigned short* __restrict__ h1, int N) {
    __shared__ short W1t[32 * 264];    // 16.9 KB: W1t[c][k] = bf16(W1[k][c])
    const int t = threadIdx.x;
    for (int i = t; i < 8192; i += 256) {
        const int k = i >> 5, c = i & 31;
        W1t[c * 264 + k] = (short)f2bf(W1[i]);
    }
    __syncthreads();

    const int l  = t & 63;
    const int wv = t >> 6;                 // wave 0..3
    const int base = blockIdx.x * 128 + wv * 32;
    const int m  = l & 31;                 // A-row / B-col lane index
    const int kh = (l >> 5) << 3;          // k half-offset: 0 or 8
    int r = base + m;
    if (r >= N) r = N - 1;                 // clamp (tail block); stores guarded
    const float* fr = feat + (size_t)r * 256 + kh;
    const short* wr = &W1t[m * 264 + kh];

    f32x16 acc;
    #pragma unroll
    for (int i = 0; i < 16; ++i) acc[i] = 0.f;

    #pragma unroll
    for (int kb = 0; kb < 16; ++kb) {
        const float4 f0 = *(const float4*)(fr + kb * 16);
        const float4 f1 = *(const float4*)(fr + kb * 16 + 4);
        bf16x8 a;
        a[0] = (short)f2bf(f0.x); a[1] = (short)f2bf(f0.y);
        a[2] = (short)f2bf(f0.z); a[3] = (short)f2bf(f0.w);
        a[4] = (short)f2bf(f1.x); a[5] = (short)f2bf(f1.y);
        a[6] = (short)f2bf(f1.z); a[7] = (short)f2bf(f1.w);
        const bf16x8 b = *(const bf16x8*)(wr + kb * 16);
        acc = __builtin_amdgcn_mfma_f32_32x32x16_bf16(a, b, acc, 0, 0, 0);
    }

    const int rbase = base + ((l >> 5) << 2);
    #pragma unroll
    for (int reg = 0; reg < 16; ++reg) {
        const int row = rbase + (reg & 3) + ((reg >> 2) << 3);
        if (row < N)
            h1[(size_t)row * 32 + m] = f2bf(acc[reg] * nsrc[row]);
    }
}

// ---- agg1: x1s[n] = bf16( relu(ndst[n]*sum h1[src] + b1) * nsrc[n] ) ------
// 64 nodes/block, 4 lanes/node, 16 B bf16x8 per lane per edge.
__global__ __launch_bounds__(256) void agg1_kernel(
    const int* __restrict__ csr_src, const int* __restrict__ rowstart,
    const int* __restrict__ indeg, const unsigned* __restrict__ h1,
    const float* __restrict__ ndst, const float* __restrict__ nsrc,
    const float* __restrict__ b1, unsigned* __restrict__ x1s, int N) {
    const int t = threadIdx.x;
    const int n = blockIdx.x * 64 + (t >> 2);
    if (n >= N) return;
    const int c = t & 3;
    const int rs = rowstart[n];
    const int re = rs + indeg[n];
    float a0=0.f,a1=0.f,a2=0.f,a3=0.f,a4=0.f,a5=0.f,a6=0.f,a7=0.f;
    const uint4* H = (const uint4*)h1;    // 4 uint4 per row
    for (int k = rs; k < re; ++k) {
        const int s = csr_src[k];
        const uint4 q = H[(size_t)s * 4 + c];
        a0 += bf_lo(q.x); a1 += bf_hi(q.x);
        a2 += bf_lo(q.y); a3 += bf_hi(q.y);
        a4 += bf_lo(q.z); a5 += bf_hi(q.z);
        a6 += bf_lo(q.w); a7 += bf_hi(q.w);
    }
    const float nd = ndst[n];
    const float ns = nsrc[n];
    const float* bb = b1 + c * 8;
    float x0 = fmaxf(a0 * nd + bb[0], 0.f) * ns;
    float x1 = fmaxf(a1 * nd + bb[1], 0.f) * ns;
    float x2 = fmaxf(a2 * nd + bb[2], 0.f) * ns;
    float x3 = fmaxf(a3 * nd + bb[3], 0.f) * ns;
    float x4 = fmaxf(a4 * nd + bb[4], 0.f) * ns;
    float x5 = fmaxf(a5 * nd + bb[5], 0.f) * ns;
    float x6 = fmaxf(a6 * nd + bb[6], 0.f) * ns;
    float x7 = fmaxf(a7 * nd + bb[7], 0.f) * ns;
    uint4 o;
    o.x = packbf2(x0, x1); o.y = packbf2(x2, x3);
    o.z = packbf2(x4, x5); o.w = packbf2(x6, x7);
    ((uint4*)x1s)[(size_t)n * 4 + c] = o;
}

// ---- agg2: a2[n] = ndst[n] * sum x1s[src]   (fp32 out, 32-wide) -----------
__global__ __launch_bounds__(256) void agg2_kernel(
    const int* __restrict__ csr_src, const int* __restrict__ rowstart,
    const int* __restrict__ indeg, const unsigned* __restrict__ x1s,
    const float* __restrict__ ndst, float* __restrict__ a2out, int N) {
    const int t = threadIdx.x;
    const int n = blockIdx.x * 64 + (t >> 2);
    if (n >= N) return;
    const int c = t & 3;
    const int rs = rowstart[n];
    const int re = rs + indeg[n];
    float a0=0.f,a1=0.f,a2=0.f,a3=0.f,a4=0.f,a5=0.f,a6=0.f,a7=0.f;
    const uint4* H = (const uint4*)x1s;
    for (int k = rs; k < re; ++k) {
        const int s = csr_src[k];
        const uint4 q = H[(size_t)s * 4 + c];
        a0 += bf_lo(q.x); a1 += bf_hi(q.x);
        a2 += bf_lo(q.y); a3 += bf_hi(q.y);
        a4 += bf_lo(q.z); a5 += bf_hi(q.z);
        a6 += bf_lo(q.w); a7 += bf_hi(q.w);
    }
    const float nd = ndst[n];
    float4 o0 = {a0 * nd, a1 * nd, a2 * nd, a3 * nd};
    float4 o1 = {a4 * nd, a5 * nd, a6 * nd, a7 * nd};
    *(float4*)&a2out[(size_t)n * 32 + c * 8] = o0;
    *(float4*)&a2out[(size_t)n * 32 + c * 8 + 4] = o1;
}

// ---- final: out = log_softmax(a2 @ W2 + b2), one wave per node ------------
__global__ __launch_bounds__(256) void final_kernel(
    const float* __restrict__ a2, const float* __restrict__ W2,
    const float* __restrict__ b2, float* __restrict__ out, int N) {
    __shared__ float sW2[32 * 40];
    __shared__ float sb2[40];
    const int t = threadIdx.x;
    for (int i = t; i < 1280; i += 256) sW2[i] = W2[i];
    if (t < 40) sb2[t] = b2[t];
    __syncthreads();
    const int lane = t & 63;
    const int n = blockIdx.x * 4 + (t >> 6);
    if (n >= N) return;
    const float v = a2[(size_t)n * 32 + (lane & 31)];
    const int jj = (lane < 40) ? lane : 39;
    float z = sb2[jj];
    #pragma unroll
    for (int k = 0; k < 32; ++k) {
        const float ak = __shfl(v, k, 64);
        z += ak * sW2[k * 40 + jj];
    }
    if (lane >= 40) z = -INFINITY;
    float m = z;
    #pragma unroll
    for (int off = 32; off; off >>= 1) m = fmaxf(m, __shfl_xor(m, off, 64));
    float e = (lane < 40) ? __expf(z - m) : 0.f;
    float s = e;
    #pragma unroll
    for (int off = 32; off; off >>= 1) s += __shfl_xor(s, off, 64);
    if (lane < 40) out[(size_t)n * 40 + lane] = z - m - __logf(s);
}

extern "C" void kernel_launch(void* const* d_in, const int* in_sizes, int n_in,
                              void* d_out, int out_size, void* d_ws, size_t ws_size,
                              hipStream_t stream) {
    const float* feat = (const float*)d_in[0];
    const int*   src  = (const int*)d_in[1];
    const int*   dst  = (const int*)d_in[2];
    const float* W1   = (const float*)d_in[3];
    const float* b1   = (const float*)d_in[4];
    const float* W2   = (const float*)d_in[5];
    const float* b2   = (const float*)d_in[6];
    float* out = (float*)d_out;

    const int N = in_sizes[0] / 256;   // 100000
    const int E = in_sizes[1];         // 3300000
    const int K = NBUCK(N);            // 391 buckets

    // layout (bytes): nsrc/ndst fp32, h1/x1s bf16 (64 B rows), a2 fp32, ints.
    char* p = (char*)d_ws;
    float* nsrc = (float*)p;                 p += (size_t)N * 4;        // 400 KB
    float* ndst = (float*)p;                 p += (size_t)N * 4;
    unsigned* h1  = (unsigned*)p;            p += (size_t)N * 64;       // 6.4 MB
    unsigned* x1s = (unsigned*)p;            p += (size_t)N * 64;       // 6.4 MB
    float* a2 = (float*)p;                   p += (size_t)N * 128;      // 12.8 MB
    int* rowstart = (int*)p;                 p += (size_t)N * 4;
    int* indeg_i  = (int*)p;                 p += (size_t)N * 4;
    int* bcntD    = (int*)p;                 p += 512 * 4;
    int* bcntS    = (int*)p;                 p += 512 * 4;
    int* bstartD  = (int*)p;                 p += 512 * 4;
    int* bstartS  = (int*)p;                 p += 512 * 4;
    int* gcurD    = (int*)p;                 p += 512 * 4;
    int* gcurS    = (int*)p;                 p += 512 * 4;
    int* csr_src  = (int*)p;                 p += (size_t)E * 4;        // 13.2 MB
    // transient overlays over [h1, x1s, a2] (dead during CSR build):
    int* gbufD = (int*)h1;                              // E ints  = 13.2 MB
    unsigned char* gbufS = (unsigned char*)h1 + (size_t)E * 4;  // E bytes = 3.3 MB

    hipMemsetAsync(bcntD, 0, sizeof(int) * 1024, stream);  // bcntD + bcntS

    const int PB = (E + TILE - 1) / TILE;

    bcount_kernel<<<PB, 256, 0, stream>>>(src, dst, bcntD, bcntS, E, K);
    bscan_kernel<<<1, 512, 0, stream>>>(bcntD, bcntS, bstartD, bstartS, gcurD, gcurS, K);
    part2_kernel<<<PB, 256, 0, stream>>>(src, dst, gcurD, gcurS, gbufD, gbufS, E, K);
    fillD_kernel<<<K, 256, 0, stream>>>(bstartD, gbufD, csr_src, rowstart, indeg_i, ndst, N, E, K);
    fillS_kernel<<<K, 256, 0, stream>>>(bstartS, gbufS, nsrc, N, E, K);

    gemm1_kernel<<<(N + 127) / 128, 256, 0, stream>>>(feat, W1, nsrc, (unsigned short*)h1, N);
    agg1_kernel<<<(N + 63) / 64, 256, 0, stream>>>(csr_src, rowstart, indeg_i, h1, ndst, nsrc, b1, x1s, N);
    agg2_kernel<<<(N + 63) / 64, 256, 0, stream>>>(csr_src, rowstart, indeg_i, x1s, ndst, a2, N);
    final_kernel<<<(N + 3) / 4, 256, 0, stream>>>(a2, W2, b2, out, N);
}

// Round 9
// 491.131 us; speedup vs baseline: 8.0289x; 1.0466x over previous
//
#include <hip/hip_runtime.h>
#include <hip/hip_bf16.h>
#include <math.h>

#define BSHIFT 8                 // 256 nodes per bucket
#define NBUCK(N) (((N) + 255) >> 8)
#define TILE 8192                // edges per partition block
#define CAP 10240                // max edges per bucket (mean 8448, 19-sigma headroom)

typedef short bf16x8 __attribute__((ext_vector_type(8)));
typedef float f32x16 __attribute__((ext_vector_type(16)));

// ---- bf16 helpers ---------------------------------------------------------
__device__ __forceinline__ unsigned short f2bf(float f) {
    unsigned u = __float_as_uint(f);
    u += 0x7fffu + ((u >> 16) & 1u);      // RNE
    return (unsigned short)(u >> 16);
}
__device__ __forceinline__ unsigned packbf2(float lo, float hi) {
    return (unsigned)f2bf(lo) | ((unsigned)f2bf(hi) << 16);
}
__device__ __forceinline__ float bf_lo(unsigned u) { return __uint_as_float(u << 16); }
__device__ __forceinline__ float bf_hi(unsigned u) { return __uint_as_float(u & 0xffff0000u); }

// ---- partition: edges -> fixed-stride dst-buckets & src-buckets -----------
// LDS-staged: histogram -> block scan -> one reservation/bucket -> LDS
// scatter -> wave-cooperative coalesced run flush (full lines, one instant).
__global__ __launch_bounds__(256) void part_kernel(
    const int* __restrict__ src, const int* __restrict__ dst,
    int* __restrict__ gcurD, int* __restrict__ gcurS,
    int* __restrict__ gbufD, unsigned char* __restrict__ gbufS, int E, int K) {
    __shared__ int cD[512], bD[512], cS[512], bS[512];
    __shared__ int oD[513], oS[513];
    __shared__ int ps[256];
    __shared__ int sbufD[TILE];              // 32 KB staging (packed entries)
    __shared__ unsigned char sbufS[TILE];    // 8 KB staging (src low bytes)
    const int t = threadIdx.x;
    const int tile = blockIdx.x * TILE;

    for (int i = t; i < 512; i += 256) { cD[i] = 0; cS[i] = 0; }
    __syncthreads();

    int dv[32];
    #pragma unroll
    for (int i = 0; i < 32; ++i) {
        const int e = tile + i * 256 + t;
        dv[i] = (e < E) ? dst[e] : -1;
        if (dv[i] >= 0) {
            atomicAdd(&cD[dv[i] >> BSHIFT], 1);
            atomicAdd(&cS[src[e] >> BSHIFT], 1);
        }
    }
    __syncthreads();

    // block-local exclusive scan of cD (512 entries, pair per thread)
    {
        const int a = cD[2 * t], b2 = cD[2 * t + 1];
        ps[t] = a + b2;
        __syncthreads();
        for (int off = 1; off < 256; off <<= 1) {
            int x = (t >= off) ? ps[t - off] : 0;
            __syncthreads(); ps[t] += x; __syncthreads();
        }
        const int base = ps[t] - a - b2;
        oD[2 * t] = base; oD[2 * t + 1] = base + a;
        if (t == 255) oD[512] = ps[255];
    }
    __syncthreads();
    // same for cS
    {
        const int a = cS[2 * t], b2 = cS[2 * t + 1];
        ps[t] = a + b2;
        __syncthreads();
        for (int off = 1; off < 256; off <<= 1) {
            int x = (t >= off) ? ps[t - off] : 0;
            __syncthreads(); ps[t] += x; __syncthreads();
        }
        const int base = ps[t] - a - b2;
        oS[2 * t] = base; oS[2 * t + 1] = base + a;
        if (t == 255) oS[512] = ps[255];
    }
    __syncthreads();

    // reserve global runs (one atomic per non-empty bucket); reset cursors
    for (int b = t; b < K; b += 256) {
        int c = oD[b + 1] - oD[b];
        bD[b] = (c ? atomicAdd(&gcurD[b], c) : 0) + b * CAP;
        cD[b] = 0;
        c = oS[b + 1] - oS[b];
        bS[b] = (c ? atomicAdd(&gcurS[b], c) : 0) + b * CAP;
        cS[b] = 0;
    }
    __syncthreads();

    // scatter into LDS staging (bucket-contiguous)
    #pragma unroll
    for (int i = 0; i < 32; ++i) {
        if (dv[i] >= 0) {
            const int e = tile + i * 256 + t;
            const int sv = src[e];
            const int b1 = dv[i] >> BSHIFT;
            const int p1 = oD[b1] + atomicAdd(&cD[b1], 1);
            sbufD[p1] = ((dv[i] & 255) << 17) | sv;
            const int b2 = sv >> BSHIFT;
            const int p2 = oS[b2] + atomicAdd(&cS[b2], 1);
            sbufS[p2] = (unsigned char)(sv & 255);
        }
    }
    __syncthreads();

    // flush runs: one wave per bucket, lanes write consecutive addresses
    const int wv = t >> 6, lane = t & 63;
    for (int b = wv; b < K; b += 4) {
        const int lb = oD[b], cnt = oD[b + 1] - lb, gb = bD[b];
        for (int j = lane; j < cnt; j += 64)
            gbufD[gb + j] = sbufD[lb + j];
    }
    for (int b = wv; b < K; b += 4) {
        const int lb = oS[b], cnt = oS[b + 1] - lb, gb = bS[b];
        for (int j = lane; j < cnt; j += 64)
            gbufS[gb + j] = sbufS[lb + j];
    }
}

// ---- fillD: per dst-bucket: indeg, rowstart, ndst, exact (CAP-strided) CSR
__global__ __launch_bounds__(256) void fillD_kernel(
    const int* __restrict__ cntD, const int* __restrict__ gbufD,
    int* __restrict__ csr_src, int* __restrict__ rowstart, int* __restrict__ indeg,
    float* __restrict__ ndst, int N, int K) {
    __shared__ int cnt[256];
    __shared__ int sc[256];
    __shared__ int cur[256];
    const int t = threadIdx.x;
    const int b = blockIdx.x;
    const int n0 = b << BSHIFT;
    const int bs = b * CAP;
    const int be = bs + cntD[b];
    cnt[t] = 0;
    __syncthreads();
    for (int idx = bs + t; idx < be; idx += 256)
        atomicAdd(&cnt[gbufD[idx] >> 17], 1);
    __syncthreads();
    const int deg = cnt[t];
    sc[t] = deg;
    __syncthreads();
    for (int off = 1; off < 256; off <<= 1) {
        int x = (t >= off) ? sc[t - off] : 0;
        __syncthreads(); sc[t] += x; __syncthreads();
    }
    const int rs = bs + sc[t] - deg;
    cur[t] = rs;
    const int n = n0 + t;
    if (n < N) {
        rowstart[n] = rs;
        indeg[n] = deg;
        ndst[n] = rsqrtf((float)deg);   // self-loops => deg >= 1
    }
    __syncthreads();
    for (int idx = bs + t; idx < be; idx += 256) {
        const int p = gbufD[idx];
        const int pos = atomicAdd(&cur[p >> 17], 1);
        csr_src[pos] = p & 131071;
    }
}

// ---- fillS: per src-bucket: outdeg -> nsrc --------------------------------
__global__ __launch_bounds__(256) void fillS_kernel(
    const int* __restrict__ cntS, const unsigned char* __restrict__ gbufS,
    float* __restrict__ nsrc, int N, int K) {
    __shared__ int cnt[256];
    const int t = threadIdx.x;
    const int b = blockIdx.x;
    const int bs = b * CAP;
    const int be = bs + cntS[b];
    cnt[t] = 0;
    __syncthreads();
    for (int idx = bs + t; idx < be; idx += 256)
        atomicAdd(&cnt[gbufS[idx]], 1);
    __syncthreads();
    const int n = (b << BSHIFT) + t;
    if (n < N) nsrc[n] = rsqrtf((float)cnt[t]);
}

// ---- GEMM1 (MFMA): h1[n][j] = bf16( nsrc[n] * sum_k feat[n][k]*W1[k][j] ) -
// 4 waves/block, 32 nodes/wave. v_mfma_f32_32x32x16_bf16, K-loop of 16.
// A straight from global; B = W1^T bf16 in LDS (row pad 264).
__global__ __launch_bounds__(256) void gemm1_kernel(
    const float* __restrict__ feat, const float* __restrict__ W1,
    const float* __restrict__ nsrc, unsigned short* __restrict__ h1, int N) {
    __shared__ short W1t[32 * 264];    // 16.9 KB: W1t[c][k] = bf16(W1[k][c])
    const int t = threadIdx.x;
    for (int i = t; i < 8192; i += 256) {
        const int k = i >> 5, c = i & 31;
        W1t[c * 264 + k] = (short)f2bf(W1[i]);
    }
    __syncthreads();

    const int l  = t & 63;
    const int wv = t >> 6;
    const int base = blockIdx.x * 128 + wv * 32;
    const int m  = l & 31;
    const int kh = (l >> 5) << 3;
    int r = base + m;
    if (r >= N) r = N - 1;
    const float* fr = feat + (size_t)r * 256 + kh;
    const short* wr = &W1t[m * 264 + kh];

    f32x16 acc;
    #pragma unroll
    for (int i = 0; i < 16; ++i) acc[i] = 0.f;

    #pragma unroll
    for (int kb = 0; kb < 16; ++kb) {
        const float4 f0 = *(const float4*)(fr + kb * 16);
        const float4 f1 = *(const float4*)(fr + kb * 16 + 4);
        bf16x8 a;
        a[0] = (short)f2bf(f0.x); a[1] = (short)f2bf(f0.y);
        a[2] = (short)f2bf(f0.z); a[3] = (short)f2bf(f0.w);
        a[4] = (short)f2bf(f1.x); a[5] = (short)f2bf(f1.y);
        a[6] = (short)f2bf(f1.z); a[7] = (short)f2bf(f1.w);
        const bf16x8 b = *(const bf16x8*)(wr + kb * 16);
        acc = __builtin_amdgcn_mfma_f32_32x32x16_bf16(a, b, acc, 0, 0, 0);
    }

    const int rbase = base + ((l >> 5) << 2);
    #pragma unroll
    for (int reg = 0; reg < 16; ++reg) {
        const int row = rbase + (reg & 3) + ((reg >> 2) << 3);
        if (row < N)
            h1[(size_t)row * 32 + m] = f2bf(acc[reg] * nsrc[row]);
    }
}

// ---- agg1: x1s[n] = bf16( relu(ndst[n]*sum h1[src] + b1) * nsrc[n] ) ------
__global__ __launch_bounds__(256) void agg1_kernel(
    const int* __restrict__ csr_src, const int* __restrict__ rowstart,
    const int* __restrict__ indeg, const unsigned* __restrict__ h1,
    const float* __restrict__ ndst, const float* __restrict__ nsrc,
    const float* __restrict__ b1, unsigned* __restrict__ x1s, int N) {
    const int t = threadIdx.x;
    const int n = blockIdx.x * 64 + (t >> 2);
    if (n >= N) return;
    const int c = t & 3;
    const int rs = rowstart[n];
    const int re = rs + indeg[n];
    float a0=0.f,a1=0.f,a2=0.f,a3=0.f,a4=0.f,a5=0.f,a6=0.f,a7=0.f;
    const uint4* H = (const uint4*)h1;
    for (int k = rs; k < re; ++k) {
        const int s = csr_src[k];
        const uint4 q = H[(size_t)s * 4 + c];
        a0 += bf_lo(q.x); a1 += bf_hi(q.x);
        a2 += bf_lo(q.y); a3 += bf_hi(q.y);
        a4 += bf_lo(q.z); a5 += bf_hi(q.z);
        a6 += bf_lo(q.w); a7 += bf_hi(q.w);
    }
    const float nd = ndst[n];
    const float ns = nsrc[n];
    const float* bb = b1 + c * 8;
    float x0 = fmaxf(a0 * nd + bb[0], 0.f) * ns;
    float x1 = fmaxf(a1 * nd + bb[1], 0.f) * ns;
    float x2 = fmaxf(a2 * nd + bb[2], 0.f) * ns;
    float x3 = fmaxf(a3 * nd + bb[3], 0.f) * ns;
    float x4 = fmaxf(a4 * nd + bb[4], 0.f) * ns;
    float x5 = fmaxf(a5 * nd + bb[5], 0.f) * ns;
    float x6 = fmaxf(a6 * nd + bb[6], 0.f) * ns;
    float x7 = fmaxf(a7 * nd + bb[7], 0.f) * ns;
    uint4 o;
    o.x = packbf2(x0, x1); o.y = packbf2(x2, x3);
    o.z = packbf2(x4, x5); o.w = packbf2(x6, x7);
    ((uint4*)x1s)[(size_t)n * 4 + c] = o;
}

// ---- agg2: a2[n] = ndst[n] * sum x1s[src]   (fp32 out, 32-wide) -----------
__global__ __launch_bounds__(256) void agg2_kernel(
    const int* __restrict__ csr_src, const int* __restrict__ rowstart,
    const int* __restrict__ indeg, const unsigned* __restrict__ x1s,
    const float* __restrict__ ndst, float* __restrict__ a2out, int N) {
    const int t = threadIdx.x;
    const int n = blockIdx.x * 64 + (t >> 2);
    if (n >= N) return;
    const int c = t & 3;
    const int rs = rowstart[n];
    const int re = rs + indeg[n];
    float a0=0.f,a1=0.f,a2=0.f,a3=0.f,a4=0.f,a5=0.f,a6=0.f,a7=0.f;
    const uint4* H = (const uint4*)x1s;
    for (int k = rs; k < re; ++k) {
        const int s = csr_src[k];
        const uint4 q = H[(size_t)s * 4 + c];
        a0 += bf_lo(q.x); a1 += bf_hi(q.x);
        a2 += bf_lo(q.y); a3 += bf_hi(q.y);
        a4 += bf_lo(q.z); a5 += bf_hi(q.z);
        a6 += bf_lo(q.w); a7 += bf_hi(q.w);
    }
    const float nd = ndst[n];
    float4 o0 = {a0 * nd, a1 * nd, a2 * nd, a3 * nd};
    float4 o1 = {a4 * nd, a5 * nd, a6 * nd, a7 * nd};
    *(float4*)&a2out[(size_t)n * 32 + c * 8] = o0;
    *(float4*)&a2out[(size_t)n * 32 + c * 8 + 4] = o1;
}

// ---- final: out = log_softmax(a2 @ W2 + b2), one wave per node ------------
__global__ __launch_bounds__(256) void final_kernel(
    const float* __restrict__ a2, const float* __restrict__ W2,
    const float* __restrict__ b2, float* __restrict__ out, int N) {
    __shared__ float sW2[32 * 40];
    __shared__ float sb2[40];
    const int t = threadIdx.x;
    for (int i = t; i < 1280; i += 256) sW2[i] = W2[i];
    if (t < 40) sb2[t] = b2[t];
    __syncthreads();
    const int lane = t & 63;
    const int n = blockIdx.x * 4 + (t >> 6);
    if (n >= N) return;
    const float v = a2[(size_t)n * 32 + (lane & 31)];
    const int jj = (lane < 40) ? lane : 39;
    float z = sb2[jj];
    #pragma unroll
    for (int k = 0; k < 32; ++k) {
        const float ak = __shfl(v, k, 64);
        z += ak * sW2[k * 40 + jj];
    }
    if (lane >= 40) z = -INFINITY;
    float m = z;
    #pragma unroll
    for (int off = 32; off; off >>= 1) m = fmaxf(m, __shfl_xor(m, off, 64));
    float e = (lane < 40) ? __expf(z - m) : 0.f;
    float s = e;
    #pragma unroll
    for (int off = 32; off; off >>= 1) s += __shfl_xor(s, off, 64);
    if (lane < 40) out[(size_t)n * 40 + lane] = z - m - __logf(s);
}

extern "C" void kernel_launch(void* const* d_in, const int* in_sizes, int n_in,
                              void* d_out, int out_size, void* d_ws, size_t ws_size,
                              hipStream_t stream) {
    const float* feat = (const float*)d_in[0];
    const int*   src  = (const int*)d_in[1];
    const int*   dst  = (const int*)d_in[2];
    const float* W1   = (const float*)d_in[3];
    const float* b1   = (const float*)d_in[4];
    const float* W2   = (const float*)d_in[5];
    const float* b2   = (const float*)d_in[6];
    float* out = (float*)d_out;

    const int N = in_sizes[0] / 256;   // 100000
    const int E = in_sizes[1];         // 3300000
    const int K = NBUCK(N);            // 391 buckets

    // layout: nsrc/ndst fp32, h1/x1s bf16 (64 B rows), a2 fp32, CSR ints.
    char* p = (char*)d_ws;
    float* nsrc = (float*)p;                 p += (size_t)N * 4;        // 400 KB
    float* ndst = (float*)p;                 p += (size_t)N * 4;
    unsigned* h1  = (unsigned*)p;            p += (size_t)N * 64;       // 6.4 MB
    unsigned* x1s = (unsigned*)p;            p += (size_t)N * 64;       // 6.4 MB
    float* a2 = (float*)p;                   p += (size_t)N * 128;      // 12.8 MB
    int* rowstart = (int*)p;                 p += (size_t)N * 4;
    int* indeg_i  = (int*)p;                 p += (size_t)N * 4;
    int* gcurD    = (int*)p;                 p += 512 * 4;
    int* gcurS    = (int*)p;                 p += 512 * 4;
    int* csr_src  = (int*)p;                 p += (size_t)K * CAP * 4;  // 16.0 MB
    // transient overlays over [h1, x1s, a2] (dead during CSR build):
    int* gbufD = (int*)h1;                                  // K*CAP ints  = 16.0 MB
    unsigned char* gbufS = (unsigned char*)h1 + (size_t)K * CAP * 4;  // K*CAP B = 4.0 MB

    hipMemsetAsync(gcurD, 0, sizeof(int) * 1024, stream);  // gcurD + gcurS

    const int PB = (E + TILE - 1) / TILE;

    part_kernel<<<PB, 256, 0, stream>>>(src, dst, gcurD, gcurS, gbufD, gbufS, E, K);
    fillD_kernel<<<K, 256, 0, stream>>>(gcurD, gbufD, csr_src, rowstart, indeg_i, ndst, N, K);
    fillS_kernel<<<K, 256, 0, stream>>>(gcurS, gbufS, nsrc, N, K);

    gemm1_kernel<<<(N + 127) / 128, 256, 0, stream>>>(feat, W1, nsrc, (unsigned short*)h1, N);
    agg1_kernel<<<(N + 63) / 64, 256, 0, stream>>>(csr_src, rowstart, indeg_i, h1, ndst, nsrc, b1, x1s, N);
    agg2_kernel<<<(N + 63) / 64, 256, 0, stream>>>(csr_src, rowstart, indeg_i, x1s, ndst, a2, N);
    final_kernel<<<(N + 3) / 4, 256, 0, stream>>>(a2, W2, b2, out, N);
}